// Round 3
// baseline (2500.750 us; speedup 1.0000x reference)
//
#include <hip/hip_runtime.h>
#include <stddef.h>

// ---------------------------------------------------------------------------
// Problem constants
// ---------------------------------------------------------------------------
#define HH 384
#define WW 384
#define CC 200
#define NN 147456      // HH*WW
#define EE 1179648
#define HIDE 128
#define COUT 64
#define NCLS 16
#define BN_EPS 1e-5f

using u16 = unsigned short;
typedef __attribute__((ext_vector_type(8))) short short8;
typedef __attribute__((ext_vector_type(4))) float float4v;

__device__ __forceinline__ float b2f(u16 u) {
    union { unsigned int i; float f; } v; v.i = ((unsigned int)u) << 16; return v.f;
}
__device__ __forceinline__ u16 f2b(float f) {
    union { float f; unsigned int i; } v; v.f = f;
    unsigned int x = v.i;
    unsigned int r = (x + 0x7fffu + ((x >> 16) & 1u)) >> 16;   // RNE
    return (u16)r;
}
__device__ __forceinline__ float lrelu(float v) { return v > 0.f ? v : 0.01f * v; }

// ---------------------------------------------------------------------------
// Dtype sniffer: bf16 N(0,1) data -> ~99% of u16 high-bytes in [0x3C,0x41];
// f32 data -> ~52%.  flag=1 means inputs are float32.
// ---------------------------------------------------------------------------
__global__ void sniff(const u16* __restrict__ x, int* __restrict__ flag) {
    __shared__ int cntS;
    if (threadIdx.x == 0) cntS = 0;
    __syncthreads();
    int c = 0;
    for (int i = 0; i < 8; i++) {
        u16 h = x[threadIdx.x * 8 + i];
        int hb = (h >> 8) & 0x7F;
        if (hb >= 0x3C && hb <= 0x41) c++;
    }
    atomicAdd(&cntS, c);
    __syncthreads();
    if (threadIdx.x == 0) *flag = (cntS < 1536) ? 1 : 0;
}

// ---------------------------------------------------------------------------
// Convert all float params into a bf16 arena (copy if already bf16).
// ---------------------------------------------------------------------------
#define NPAR 27
struct PConv { const void* src[NPAR]; int n[NPAR]; int off[NPAR]; };

__global__ void convert_params(PConv pc, const int* __restrict__ flag,
                               u16* __restrict__ dst) {
    int b = blockIdx.x;
    int n = pc.n[b];
    const void* s = pc.src[b];
    u16* d = dst + pc.off[b];
    int isf = *flag;
    if (isf) {
        const float* sf = (const float*)s;
        for (int i = threadIdx.x; i < n; i += 256) d[i] = f2b(sf[i]);
    } else {
        const u16* sh = (const u16*)s;
        for (int i = threadIdx.x; i < n; i += 256) d[i] = sh[i];
    }
}

// ---------------------------------------------------------------------------
// Column stats (sum, sumsq) for BN folding
// ---------------------------------------------------------------------------
__global__ void stats200(const void* __restrict__ X, const int* __restrict__ flag,
                         float* __restrict__ arena) {
    int t = threadIdx.x;
    if (t >= CC) return;
    int r0 = blockIdx.x * 288;
    float s = 0.f, q = 0.f;
    if (*flag) {
        const float* Xf = (const float*)X;
        for (int i = 0; i < 288; i++) {
            float v = Xf[(size_t)(r0 + i) * CC + t];
            s += v; q += v * v;
        }
    } else {
        const u16* Xh = (const u16*)X;
        for (int i = 0; i < 288; i++) {
            float v = b2f(Xh[(size_t)(r0 + i) * CC + t]);
            s += v; q += v * v;
        }
    }
    atomicAdd(&arena[t], s);
    atomicAdd(&arena[256 + t], q);
}

__global__ void stats128(const u16* __restrict__ X, float* __restrict__ arena) {
    int t = threadIdx.x;
    int f = t & 127, half = t >> 7;
    int r0 = blockIdx.x * 256 + half;
    float s = 0.f, q = 0.f;
    for (int i = 0; i < 128; i++) {
        float v = b2f(X[(size_t)(r0 + 2 * i) * HIDE + f]);
        s += v; q += v * v;
    }
    atomicAdd(&arena[f], s);
    atomicAdd(&arena[256 + f], q);
}

// Per-row L2 inverse norm + column stats of row-normalized values.
__global__ void rowstats(const u16* __restrict__ X, float* __restrict__ invnorm,
                         float* __restrict__ arena) {
    int wid = blockIdx.x * 4 + (threadIdx.x >> 6);
    int lane = threadIdx.x & 63;
    int r0 = wid * 144;
    float s0 = 0.f, q0 = 0.f, s1 = 0.f, q1 = 0.f;
    for (int i = 0; i < 144; i++) {
        int r = r0 + i;
        float v0 = b2f(X[(size_t)r * HIDE + lane]);
        float v1 = b2f(X[(size_t)r * HIDE + 64 + lane]);
        float ss = v0 * v0 + v1 * v1;
        #pragma unroll
        for (int o = 32; o >= 1; o >>= 1) ss += __shfl_xor(ss, o);
        float inv = 1.0f / fmaxf(sqrtf(ss), 1e-12f);
        if (lane == 0) invnorm[r] = inv;
        v0 *= inv; v1 *= inv;
        s0 += v0; q0 += v0 * v0;
        s1 += v1; q1 += v1 * v1;
    }
    atomicAdd(&arena[lane], s0);
    atomicAdd(&arena[64 + lane], s1);
    atomicAdd(&arena[256 + lane], q0);
    atomicAdd(&arena[256 + 64 + lane], q1);
}

// ---------------------------------------------------------------------------
// Fold BN affine into weights: W'[k,o]=a[k]*W[k,o]; cb[o]=sum_k shift[k]*W[k,o]
// Writes W' TRANSPOSED [O, KPAD] (zero padded K..KPAD).
// ---------------------------------------------------------------------------
template<int K, int KPAD, int O>
__global__ void fold_bn(const float* __restrict__ arena, float invN,
                        const u16* __restrict__ bng, const u16* __restrict__ bnb,
                        const u16* __restrict__ Wsrc, const u16* __restrict__ extrab,
                        u16* __restrict__ WT, float* __restrict__ cb) {
    __shared__ float aS[KPAD], sS[KPAD];
    int t = threadIdx.x;
    if (t < KPAD) {
        float a = 0.f, sh = 0.f;
        if (t < K) {
            float m = arena[t] * invN;
            float var = fmaxf(arena[256 + t] * invN - m * m, 0.f);
            a = b2f(bng[t]) * rsqrtf(var + BN_EPS);
            sh = b2f(bnb[t]) - m * a;
        }
        aS[t] = a; sS[t] = sh;
    }
    __syncthreads();
    if (t < O) {
        float c = extrab ? b2f(extrab[t]) : 0.f;
        for (int k = 0; k < KPAD; k++) {
            float w = (k < K) ? b2f(Wsrc[k * O + t]) : 0.f;
            c += sS[k] * w;
            WT[t * KPAD + k] = f2b(aS[k] * w);
        }
        cb[t] = c;
    }
}

// ---------------------------------------------------------------------------
// MFMA GEMM: out[N,O] = post( rowscale? * (A[N,KSRC] @ W') + cb )
// 64 rows x O cols per block, 4 waves.  f32p non-null => A may be f32 (branch).
// ---------------------------------------------------------------------------
template<int KT, int KSRC, int O, bool LEAKY, bool SCALE>
__global__ __launch_bounds__(256) void gemm_mfma(
        const void* __restrict__ Ap, const u16* __restrict__ WT,
        const float* __restrict__ cb, const float* __restrict__ rowscale,
        const int* __restrict__ f32p, u16* __restrict__ out) {
    constexpr int KPAD = KT * 32;
    constexpr int LDA = KPAD + 8;
    __shared__ __align__(16) u16 As[64 * LDA];
    int tid = threadIdx.x;
    int row0 = blockIdx.x * 64;

    if constexpr (KSRC == KPAD) {
        const u16* A = (const u16*)Ap;
        constexpr int CH = 64 * KPAD / 8;
        for (int i = tid; i < CH; i += 256) {
            int r = i / (KPAD / 8), kc = i % (KPAD / 8);
            short8 v = *(const short8*)(A + (size_t)(row0 + r) * KSRC + kc * 8);
            *(short8*)&As[r * LDA + kc * 8] = v;
        }
    } else {
        int isf = f32p ? *f32p : 0;
        if (isf) {
            const float* A = (const float*)Ap;
            for (int i = tid; i < 64 * KPAD; i += 256) {
                int r = i / KPAD, k = i - r * KPAD;
                As[r * LDA + k] = (k < KSRC) ? f2b(A[(size_t)(row0 + r) * KSRC + k]) : (u16)0;
            }
        } else {
            const u16* A = (const u16*)Ap;
            for (int i = tid; i < 64 * KPAD; i += 256) {
                int r = i / KPAD, k = i - r * KPAD;
                As[r * LDA + k] = (k < KSRC) ? A[(size_t)(row0 + r) * KSRC + k] : (u16)0;
            }
        }
    }
    __syncthreads();

    int w = tid >> 6, lane = tid & 63, m = lane & 15, q = lane >> 4;
    const u16* Ab = &As[(w * 16 + m) * LDA];
    short8 af[KT];
    #pragma unroll
    for (int kt = 0; kt < KT; kt++) af[kt] = *(const short8*)(Ab + kt * 32 + q * 8);

    #pragma unroll
    for (int ct = 0; ct < O / 16; ct++) {
        float4v acc = {0.f, 0.f, 0.f, 0.f};
        const u16* Bb = WT + (size_t)(ct * 16 + m) * KPAD + q * 8;
        #pragma unroll
        for (int kt = 0; kt < KT; kt++) {
            short8 bf = *(const short8*)(Bb + kt * 32);
            acc = __builtin_amdgcn_mfma_f32_16x16x32_bf16(af[kt], bf, acc, 0, 0, 0);
        }
        float cbv = cb[ct * 16 + m];
        #pragma unroll
        for (int r = 0; r < 4; r++) {
            int rowg = row0 + w * 16 + q * 4 + r;
            float v = acc[r];
            if constexpr (SCALE) v *= rowscale[rowg];
            v += cbv;
            if constexpr (LEAKY) v = lrelu(v);
            out[(size_t)rowg * O + ct * 16 + m] = f2b(v);
        }
    }
}

// ---------------------------------------------------------------------------
// Edge preprocessing: histogram -> dinv -> exclusive scan -> CSR scatter
// ---------------------------------------------------------------------------
__global__ void hist(const int* __restrict__ dst, int* __restrict__ cnt) {
    int e = blockIdx.x * 256 + threadIdx.x;
    unsigned d = (unsigned)dst[e];
    if (d < (unsigned)NN) atomicAdd(&cnt[d], 1);
}
__global__ void mkdinv(const int* __restrict__ cnt, float* __restrict__ dinv) {
    int i = blockIdx.x * 256 + threadIdx.x;
    int c = cnt[i]; if (c < 0) c = 0;
    dinv[i] = rsqrtf((float)c + 1.0f);     // +1 self loop
}
__global__ void scan_part(const int* __restrict__ cnt, int* __restrict__ bsum) {
    int b = blockIdx.x, t = threadIdx.x;
    int base = b * 1024 + t * 4;
    int s = cnt[base] + cnt[base + 1] + cnt[base + 2] + cnt[base + 3];
    #pragma unroll
    for (int o = 32; o >= 1; o >>= 1) s += __shfl_down(s, o);
    __shared__ int ws4[4];
    if ((t & 63) == 0) ws4[t >> 6] = s;
    __syncthreads();
    if (t == 0) bsum[b] = ws4[0] + ws4[1] + ws4[2] + ws4[3];
}
__global__ void scan_top(const int* __restrict__ bsum, int* __restrict__ boff) {
    if (threadIdx.x == 0) {
        int a = 0;
        for (int i = 0; i < 144; i++) { boff[i] = a; a += bsum[i]; }
    }
}
__global__ void scan_write(const int* __restrict__ cnt, const int* __restrict__ boff,
                           int* __restrict__ offv) {
    int b = blockIdx.x, t = threadIdx.x;
    int base = b * 1024 + t * 4;
    int v0 = cnt[base], v1 = cnt[base + 1], v2 = cnt[base + 2], v3 = cnt[base + 3];
    int ts = v0 + v1 + v2 + v3;
    __shared__ int sc[256];
    sc[t] = ts;
    __syncthreads();
    for (int o = 1; o < 256; o <<= 1) {
        int x = (t >= o) ? sc[t - o] : 0;
        __syncthreads();
        sc[t] += x;
        __syncthreads();
    }
    int excl = boff[b] + sc[t] - ts;
    offv[base] = excl;
    offv[base + 1] = excl + v0;
    offv[base + 2] = excl + v0 + v1;
    offv[base + 3] = excl + v0 + v1 + v2;
    if (b == 143 && t == 255) offv[NN] = excl + ts;
}
__global__ void scatter(const int* __restrict__ src, const int* __restrict__ dst,
                        int* __restrict__ cursor, const int* __restrict__ offv,
                        int* __restrict__ csr) {
    int e = blockIdx.x * 256 + threadIdx.x;
    unsigned d = (unsigned)dst[e];
    if (d >= (unsigned)NN) return;
    int p = atomicAdd(&cursor[d], 1);
    unsigned idx = (unsigned)(offv[d] + p);
    if (idx < (unsigned)EE) csr[idx] = src[e];     // guard: identity when correct
}

// ---------------------------------------------------------------------------
// GCN aggregation: out[d] = leaky( dinv[d]*sum_s dinv[s]*h[s] + dinv[d]^2*h[d] + b )
// ---------------------------------------------------------------------------
template<int O>
__global__ void aggregate(const u16* __restrict__ h, const int* __restrict__ offv,
                          const int* __restrict__ csr, const float* __restrict__ dinv,
                          const u16* __restrict__ gb, u16* __restrict__ outp) {
    int t = threadIdx.x;
    int d = blockIdx.x * (256 / O) + t / O;
    int f = t & (O - 1);
    float acc = 0.f;
    int e0 = offv[d], e1 = offv[d + 1];
    if (e0 < 0) e0 = 0;
    if (e1 > EE) e1 = EE;
    for (int k = e0; k < e1; k++) {
        unsigned s = (unsigned)csr[k];
        if (s < (unsigned)NN)
            acc += dinv[s] * b2f(h[(size_t)s * O + f]);
    }
    float dd = dinv[d];
    float v = dd * acc + dd * dd * b2f(h[(size_t)d * O + f]) + b2f(gb[f]);
    outp[(size_t)d * O + f] = f2b(lrelu(v));
}

// ---------------------------------------------------------------------------
// Fused: depthwise 5x5 (SAME, zero pad) on c[H,W,64] + concat with g3 ->
// linear 128->16 -> softmax.  16x16 pixel tile + 2-halo in LDS.
// Output dtype follows the flag (f32 vs bf16).
// ---------------------------------------------------------------------------
__global__ __launch_bounds__(256) void final_fused(
        const u16* __restrict__ g3, const u16* __restrict__ cpre,
        const u16* __restrict__ dwW, const u16* __restrict__ db,
        const u16* __restrict__ lw, const u16* __restrict__ lb,
        const int* __restrict__ flag, void* __restrict__ outp) {
    __shared__ __align__(16) u16 tile[20 * 20 * 64];   // 51200 B
    __shared__ u16 wDW[1600];
    __shared__ float bDW[64];
    __shared__ u16 wL[2048];
    __shared__ float bL[16];
    int t = threadIdx.x;
    int tx = blockIdx.x % 24, ty = blockIdx.x / 24;
    int x0 = tx * 16 - 2, y0 = ty * 16 - 2;
    for (int i = t; i < 1600; i += 256) wDW[i] = dwW[i];
    for (int i = t; i < 2048; i += 256) wL[i] = lw[i];
    if (t < 64) bDW[t] = b2f(db[t]);
    if (t < 16) bL[t] = b2f(lb[t]);
    for (int i = t; i < 25600; i += 256) {
        int ch = i & 63, pix = i >> 6;
        int gy = y0 + pix / 20, gx = x0 + pix % 20;
        u16 v = 0;
        if (gy >= 0 && gy < HH && gx >= 0 && gx < WW)
            v = cpre[((size_t)(gy * WW + gx)) * 64 + ch];
        tile[i] = v;
    }
    __syncthreads();
    int px = t & 15, py = t >> 4;
    int node = (ty * 16 + py) * WW + tx * 16 + px;
    float y[16];
    #pragma unroll
    for (int o = 0; o < 16; o++) y[o] = bL[o];
    const u16* g3p = g3 + (size_t)node * 64;
    for (int f = 0; f < 64; f++) {
        float gv = b2f(g3p[f]);
        #pragma unroll
        for (int o = 0; o < 16; o++) y[o] += gv * b2f(wL[f * 16 + o]);
    }
    for (int f = 0; f < 64; f++) {
        float acc = 0.f;
        #pragma unroll
        for (int dy = 0; dy < 5; dy++)
            #pragma unroll
            for (int dx = 0; dx < 5; dx++)
                acc += b2f(tile[((py + dy) * 20 + (px + dx)) * 64 + f]) *
                       b2f(wDW[f * 25 + dy * 5 + dx]);
        float cv = lrelu(acc + bDW[f]);
        #pragma unroll
        for (int o = 0; o < 16; o++) y[o] += cv * b2f(wL[(64 + f) * 16 + o]);
    }
    float mx = y[0];
    #pragma unroll
    for (int o = 1; o < 16; o++) mx = fmaxf(mx, y[o]);
    float sum = 0.f;
    #pragma unroll
    for (int o = 0; o < 16; o++) { y[o] = __expf(y[o] - mx); sum += y[o]; }
    float inv = 1.0f / fmaxf(sum, 1e-30f);
    if (*flag) {
        float* of = (float*)outp;
        #pragma unroll
        for (int o = 0; o < 16; o++) of[(size_t)node * 16 + o] = y[o] * inv;
    } else {
        u16* oh = (u16*)outp;
        #pragma unroll
        for (int o = 0; o < 16; o++) oh[(size_t)node * 16 + o] = f2b(y[o] * inv);
    }
}

// ---------------------------------------------------------------------------
// Host launcher
// ---------------------------------------------------------------------------
extern "C" void kernel_launch(void* const* d_in, const int* in_sizes, int n_in,
                              void* d_out, int out_size, void* d_ws, size_t ws_size,
                              hipStream_t stream) {
    const void* X   = d_in[0];
    const int* EIDX = (const int*)d_in[1];
    const int* esrc = EIDX;
    const int* edst = EIDX + EE;

    char* ws = (char*)d_ws;
    size_t off = 0;
    auto alloc = [&](size_t sz) -> char* {
        size_t szr = (sz + 255) & ~(size_t)255;
        char* p;
        if (off + szr <= ws_size) { p = ws + off; off += szr; }
        else { p = ws; }   // ws too small: alias at base -> finite-wrong diagnostic
        return p;
    };

    // Small control/param data first (fits any sane ws).
    int*   dflag   = (int*)alloc(256);
    // param arena
    static const int pidx[NPAR] = {2,3,4,5,6,7,8,9,10,11,12,13,14,
                                   15,16,17,18,19,20,21,22,23,24,25,26,27,28};
    static const int pn[NPAR]   = {200,200,25600,128,128,128,16384,128,
                                   128,128,8192,1600,64,
                                   128,128,16384,128,
                                   128,128,16384,128,
                                   128,128,8192,64,
                                   2048,16};
    u16* parena = (u16*)alloc(100352 * 2);
    PConv pc;
    {
        int po = 0;
        for (int i = 0; i < NPAR; i++) {
            pc.src[i] = d_in[pidx[i]];
            pc.n[i] = pn[i];
            pc.off[i] = po;
            po += (pn[i] + 15) & ~15;
        }
    }
    const u16* DN1G = parena + pc.off[0];
    const u16* DN1B = parena + pc.off[1];
    const u16* DNW1 = parena + pc.off[2];
    const u16* DNB1 = parena + pc.off[3];
    const u16* DN2G = parena + pc.off[4];
    const u16* DN2B = parena + pc.off[5];
    const u16* DNW2 = parena + pc.off[6];
    const u16* DNB2 = parena + pc.off[7];
    const u16* CBNG = parena + pc.off[8];
    const u16* CBNB = parena + pc.off[9];
    const u16* CPW  = parena + pc.off[10];
    const u16* CDW  = parena + pc.off[11];
    const u16* CDB  = parena + pc.off[12];
    const u16* G1G  = parena + pc.off[13];
    const u16* G1B  = parena + pc.off[14];
    const u16* G1W  = parena + pc.off[15];
    const u16* G1BI = parena + pc.off[16];
    const u16* G2G  = parena + pc.off[17];
    const u16* G2B  = parena + pc.off[18];
    const u16* G2W  = parena + pc.off[19];
    const u16* G2BI = parena + pc.off[20];
    const u16* G3G  = parena + pc.off[21];
    const u16* G3B  = parena + pc.off[22];
    const u16* G3W  = parena + pc.off[23];
    const u16* G3BI = parena + pc.off[24];
    const u16* LINW = parena + pc.off[25];
    const u16* LINB = parena + pc.off[26];

    // zero region (contiguous)
    int*   cnt     = (int*)alloc((size_t)NN * 4);
    int*   cursor  = (int*)alloc((size_t)NN * 4);
    float* arena   = (float*)alloc(6 * 512 * 4);
    // ---- end zero region ----
    int*   offv    = (int*)alloc((size_t)(NN + 1) * 4);
    int*   bsum    = (int*)alloc(144 * 4);
    int*   boff    = (int*)alloc(144 * 4);
    float* dinvp   = (float*)alloc((size_t)NN * 4);
    float* invnorm = (float*)alloc((size_t)NN * 4);
    u16*   W1T     = (u16*)alloc(128 * 224 * 2);
    u16*   W2T     = (u16*)alloc(128 * 128 * 2);
    u16*   WpwT    = (u16*)alloc(64 * 128 * 2);
    u16*   WgT     = (u16*)alloc(128 * 128 * 2);
    float* cb1     = (float*)alloc(128 * 4);
    float* cb2     = (float*)alloc(128 * 4);
    float* cb3     = (float*)alloc(128 * 4);
    float* cbg     = (float*)alloc(128 * 4);
    int*   csr     = (int*)alloc((size_t)EE * 4);
    u16*   cbuf    = (u16*)alloc((size_t)NN * 64 * 2);    // CNN pre-dwconv "c"
    u16*   big1    = (u16*)alloc((size_t)NN * 128 * 2);   // h scratch
    u16*   big2    = (u16*)alloc((size_t)NN * 128 * 2);   // clean / g1 / g2 / g3

    const float invN = 1.0f / (float)NN;
    size_t zsz = (size_t)((char*)(arena + 6 * 512) - (char*)cnt);
    size_t zcap = ((char*)cnt >= ws && (size_t)((char*)cnt - ws) < ws_size)
                      ? ws_size - (size_t)((char*)cnt - ws) : 0;
    if (zsz > zcap) zsz = zcap;
    hipMemsetAsync(cnt, 0, zsz, stream);

    // --- dtype detection + param conversion ---
    sniff<<<1, 256, 0, stream>>>((const u16*)X, dflag);
    convert_params<<<NPAR, 256, 0, stream>>>(pc, dflag, parena);

    // --- denoise ---
    stats200<<<512, 256, 0, stream>>>(X, dflag, arena + 0 * 512);
    fold_bn<200, 224, 128><<<1, 256, 0, stream>>>(arena + 0 * 512, invN, DN1G, DN1B, DNW1, DNB1, W1T, cb1);
    gemm_mfma<7, 200, 128, true, false><<<NN / 64, 256, 0, stream>>>(X, W1T, cb1, nullptr, dflag, big1);
    stats128<<<576, 256, 0, stream>>>(big1, arena + 1 * 512);
    fold_bn<128, 128, 128><<<1, 256, 0, stream>>>(arena + 1 * 512, invN, DN2G, DN2B, DNW2, DNB2, W2T, cb2);
    gemm_mfma<4, 128, 128, true, false><<<NN / 64, 256, 0, stream>>>(big1, W2T, cb2, nullptr, nullptr, big2);

    // --- CNN branch pointwise (dwconv fused into final) ---
    stats128<<<576, 256, 0, stream>>>(big2, arena + 2 * 512);
    fold_bn<128, 128, 64><<<1, 256, 0, stream>>>(arena + 2 * 512, invN, CBNG, CBNB, CPW, nullptr, WpwT, cb3);
    gemm_mfma<4, 128, 64, true, false><<<NN / 64, 256, 0, stream>>>(big2, WpwT, cb3, nullptr, nullptr, cbuf);

    // --- edge preprocessing (CSR) ---
    hist<<<EE / 256, 256, 0, stream>>>(edst, cnt);
    mkdinv<<<NN / 256, 256, 0, stream>>>(cnt, dinvp);
    scan_part<<<144, 256, 0, stream>>>(cnt, bsum);
    scan_top<<<1, 64, 0, stream>>>(bsum, boff);
    scan_write<<<144, 256, 0, stream>>>(cnt, boff, offv);
    scatter<<<EE / 256, 256, 0, stream>>>(esrc, edst, cursor, offv, csr);

    // --- GCN layer 1: big2(clean) -> big1(h) -> big2(g1) ---
    rowstats<<<256, 256, 0, stream>>>(big2, invnorm, arena + 3 * 512);
    fold_bn<128, 128, 128><<<1, 256, 0, stream>>>(arena + 3 * 512, invN, G1G, G1B, G1W, nullptr, WgT, cbg);
    gemm_mfma<4, 128, 128, false, true><<<NN / 64, 256, 0, stream>>>(big2, WgT, cbg, invnorm, nullptr, big1);
    aggregate<128><<<NN / 2, 256, 0, stream>>>(big1, offv, csr, dinvp, G1BI, big2);

    // --- GCN layer 2 ---
    rowstats<<<256, 256, 0, stream>>>(big2, invnorm, arena + 4 * 512);
    fold_bn<128, 128, 128><<<1, 256, 0, stream>>>(arena + 4 * 512, invN, G2G, G2B, G2W, nullptr, WgT, cbg);
    gemm_mfma<4, 128, 128, false, true><<<NN / 64, 256, 0, stream>>>(big2, WgT, cbg, invnorm, nullptr, big1);
    aggregate<128><<<NN / 2, 256, 0, stream>>>(big1, offv, csr, dinvp, G2BI, big2);

    // --- GCN layer 3 (128 -> 64) ---
    rowstats<<<256, 256, 0, stream>>>(big2, invnorm, arena + 5 * 512);
    fold_bn<128, 128, 64><<<1, 256, 0, stream>>>(arena + 5 * 512, invN, G3G, G3B, G3W, nullptr, WgT, cbg);
    gemm_mfma<4, 128, 64, false, true><<<NN / 64, 256, 0, stream>>>(big2, WgT, cbg, invnorm, nullptr, big1);
    aggregate<64><<<NN / 4, 256, 0, stream>>>(big1, offv, csr, dinvp, G3BI, big2);

    // --- fused dwconv + final linear + softmax ---
    final_fused<<<576, 256, 0, stream>>>(big2, cbuf, CDW, CDB, LINW, LINB, dflag, d_out);

    (void)in_sizes; (void)n_in; (void)out_size;
}

// Round 4
// 1443.763 us; speedup vs baseline: 1.7321x; 1.7321x over previous
//
#include <hip/hip_runtime.h>
#include <stddef.h>

// ---------------------------------------------------------------------------
// Problem constants
// ---------------------------------------------------------------------------
#define HH 384
#define WW 384
#define CC 200
#define NN 147456      // HH*WW
#define EE 1179648
#define HIDE 128
#define COUT 64
#define NCLS 16
#define BN_EPS 1e-5f

using u16 = unsigned short;
typedef __attribute__((ext_vector_type(8))) short short8;
typedef __attribute__((ext_vector_type(4))) float float4v;

__device__ __forceinline__ float b2f(u16 u) {
    union { unsigned int i; float f; } v; v.i = ((unsigned int)u) << 16; return v.f;
}
__device__ __forceinline__ u16 f2b(float f) {
    union { float f; unsigned int i; } v; v.f = f;
    unsigned int x = v.i;
    unsigned int r = (x + 0x7fffu + ((x >> 16) & 1u)) >> 16;   // RNE
    return (u16)r;
}
__device__ __forceinline__ float lrelu(float v) { return v > 0.f ? v : 0.01f * v; }

// ---------------------------------------------------------------------------
// Dtype sniffer: bf16 N(0,1) data -> ~99% of u16 high-bytes in [0x3C,0x41];
// f32 data -> ~52%.  flag=1 means inputs are float32.
// ---------------------------------------------------------------------------
__global__ void sniff(const u16* __restrict__ x, int* __restrict__ flag) {
    __shared__ int cntS;
    if (threadIdx.x == 0) cntS = 0;
    __syncthreads();
    int c = 0;
    for (int i = 0; i < 8; i++) {
        u16 h = x[threadIdx.x * 8 + i];
        int hb = (h >> 8) & 0x7F;
        if (hb >= 0x3C && hb <= 0x41) c++;
    }
    atomicAdd(&cntS, c);
    __syncthreads();
    if (threadIdx.x == 0) *flag = (cntS < 1536) ? 1 : 0;
}

// ---------------------------------------------------------------------------
// Convert all float params into a bf16 arena (copy if already bf16).
// ---------------------------------------------------------------------------
#define NPAR 27
struct PConv { const void* src[NPAR]; int n[NPAR]; int off[NPAR]; };

__global__ void convert_params(PConv pc, const int* __restrict__ flag,
                               u16* __restrict__ dst) {
    int b = blockIdx.x;
    int n = pc.n[b];
    const void* s = pc.src[b];
    u16* d = dst + pc.off[b];
    int isf = *flag;
    if (isf) {
        const float* sf = (const float*)s;
        for (int i = threadIdx.x; i < n; i += 256) d[i] = f2b(sf[i]);
    } else {
        const u16* sh = (const u16*)s;
        for (int i = threadIdx.x; i < n; i += 256) d[i] = sh[i];
    }
}

// ---------------------------------------------------------------------------
// Column stats (sum, sumsq) for BN folding
// ---------------------------------------------------------------------------
__global__ void stats200(const void* __restrict__ X, const int* __restrict__ flag,
                         float* __restrict__ arena) {
    int t = threadIdx.x;
    if (t >= CC) return;
    int r0 = blockIdx.x * 288;
    float s = 0.f, q = 0.f;
    if (*flag) {
        const float* Xf = (const float*)X;
        for (int i = 0; i < 288; i++) {
            float v = Xf[(size_t)(r0 + i) * CC + t];
            s += v; q += v * v;
        }
    } else {
        const u16* Xh = (const u16*)X;
        for (int i = 0; i < 288; i++) {
            float v = b2f(Xh[(size_t)(r0 + i) * CC + t]);
            s += v; q += v * v;
        }
    }
    atomicAdd(&arena[t], s);
    atomicAdd(&arena[256 + t], q);
}

__global__ void stats128(const u16* __restrict__ X, float* __restrict__ arena) {
    int t = threadIdx.x;
    int f = t & 127, half = t >> 7;
    int r0 = blockIdx.x * 256 + half;
    float s = 0.f, q = 0.f;
    for (int i = 0; i < 128; i++) {
        float v = b2f(X[(size_t)(r0 + 2 * i) * HIDE + f]);
        s += v; q += v * v;
    }
    atomicAdd(&arena[f], s);
    atomicAdd(&arena[256 + f], q);
}

// Per-row L2 inverse norm + column stats of row-normalized values.
__global__ void rowstats(const u16* __restrict__ X, float* __restrict__ invnorm,
                         float* __restrict__ arena) {
    int wid = blockIdx.x * 4 + (threadIdx.x >> 6);
    int lane = threadIdx.x & 63;
    int r0 = wid * 144;
    float s0 = 0.f, q0 = 0.f, s1 = 0.f, q1 = 0.f;
    for (int i = 0; i < 144; i++) {
        int r = r0 + i;
        float v0 = b2f(X[(size_t)r * HIDE + lane]);
        float v1 = b2f(X[(size_t)r * HIDE + 64 + lane]);
        float ss = v0 * v0 + v1 * v1;
        #pragma unroll
        for (int o = 32; o >= 1; o >>= 1) ss += __shfl_xor(ss, o);
        float inv = 1.0f / fmaxf(sqrtf(ss), 1e-12f);
        if (lane == 0) invnorm[r] = inv;
        v0 *= inv; v1 *= inv;
        s0 += v0; q0 += v0 * v0;
        s1 += v1; q1 += v1 * v1;
    }
    atomicAdd(&arena[lane], s0);
    atomicAdd(&arena[64 + lane], s1);
    atomicAdd(&arena[256 + lane], q0);
    atomicAdd(&arena[256 + 64 + lane], q1);
}

// ---------------------------------------------------------------------------
// Fold BN affine into weights: W'[k,o]=a[k]*W[k,o]; cb[o]=sum_k shift[k]*W[k,o]
// Writes W' TRANSPOSED [O, KPAD] (zero padded K..KPAD).
// ---------------------------------------------------------------------------
template<int K, int KPAD, int O>
__global__ void fold_bn(const float* __restrict__ arena, float invN,
                        const u16* __restrict__ bng, const u16* __restrict__ bnb,
                        const u16* __restrict__ Wsrc, const u16* __restrict__ extrab,
                        u16* __restrict__ WT, float* __restrict__ cb) {
    __shared__ float aS[KPAD], sS[KPAD];
    int t = threadIdx.x;
    if (t < KPAD) {
        float a = 0.f, sh = 0.f;
        if (t < K) {
            float m = arena[t] * invN;
            float var = fmaxf(arena[256 + t] * invN - m * m, 0.f);
            a = b2f(bng[t]) * rsqrtf(var + BN_EPS);
            sh = b2f(bnb[t]) - m * a;
        }
        aS[t] = a; sS[t] = sh;
    }
    __syncthreads();
    if (t < O) {
        float c = extrab ? b2f(extrab[t]) : 0.f;
        for (int k = 0; k < KPAD; k++) {
            float w = (k < K) ? b2f(Wsrc[k * O + t]) : 0.f;
            c += sS[k] * w;
            WT[t * KPAD + k] = f2b(aS[k] * w);
        }
        cb[t] = c;
    }
}

// ---------------------------------------------------------------------------
// MFMA GEMM: out[N,O] = post( ... )
// SCALE=false: v = acc + cb  (+leaky if LEAKY)
// SCALE=true : v = (acc*s1[row] + cb) * s2[row]   (GCN: s1=invnorm, s2=dinv)
// ---------------------------------------------------------------------------
template<int KT, int KSRC, int O, bool LEAKY, bool SCALE>
__global__ __launch_bounds__(256) void gemm_mfma(
        const void* __restrict__ Ap, const u16* __restrict__ WT,
        const float* __restrict__ cb, const float* __restrict__ s1,
        const float* __restrict__ s2, const int* __restrict__ f32p,
        u16* __restrict__ out) {
    constexpr int KPAD = KT * 32;
    constexpr int LDA = KPAD + 8;
    __shared__ __align__(16) u16 As[64 * LDA];
    int tid = threadIdx.x;
    int row0 = blockIdx.x * 64;

    if constexpr (KSRC == KPAD) {
        const u16* A = (const u16*)Ap;
        constexpr int CH = 64 * KPAD / 8;
        for (int i = tid; i < CH; i += 256) {
            int r = i / (KPAD / 8), kc = i % (KPAD / 8);
            short8 v = *(const short8*)(A + (size_t)(row0 + r) * KSRC + kc * 8);
            *(short8*)&As[r * LDA + kc * 8] = v;
        }
    } else {
        int isf = f32p ? *f32p : 0;
        if (isf) {
            const float* A = (const float*)Ap;
            for (int i = tid; i < 64 * KPAD; i += 256) {
                int r = i / KPAD, k = i - r * KPAD;
                As[r * LDA + k] = (k < KSRC) ? f2b(A[(size_t)(row0 + r) * KSRC + k]) : (u16)0;
            }
        } else {
            const u16* A = (const u16*)Ap;
            for (int i = tid; i < 64 * KPAD; i += 256) {
                int r = i / KPAD, k = i - r * KPAD;
                As[r * LDA + k] = (k < KSRC) ? A[(size_t)(row0 + r) * KSRC + k] : (u16)0;
            }
        }
    }
    __syncthreads();

    int w = tid >> 6, lane = tid & 63, m = lane & 15, q = lane >> 4;
    const u16* Ab = &As[(w * 16 + m) * LDA];
    short8 af[KT];
    #pragma unroll
    for (int kt = 0; kt < KT; kt++) af[kt] = *(const short8*)(Ab + kt * 32 + q * 8);

    #pragma unroll
    for (int ct = 0; ct < O / 16; ct++) {
        float4v acc = {0.f, 0.f, 0.f, 0.f};
        const u16* Bb = WT + (size_t)(ct * 16 + m) * KPAD + q * 8;
        #pragma unroll
        for (int kt = 0; kt < KT; kt++) {
            short8 bf = *(const short8*)(Bb + kt * 32);
            acc = __builtin_amdgcn_mfma_f32_16x16x32_bf16(af[kt], bf, acc, 0, 0, 0);
        }
        float cbv = cb[ct * 16 + m];
        #pragma unroll
        for (int r = 0; r < 4; r++) {
            int rowg = row0 + w * 16 + q * 4 + r;
            float v = acc[r];
            if constexpr (SCALE) v = (v * s1[rowg] + cbv) * s2[rowg];
            else                 v += cbv;
            if constexpr (LEAKY) v = lrelu(v);
            out[(size_t)rowg * O + ct * 16 + m] = f2b(v);
        }
    }
}

// ---------------------------------------------------------------------------
// Edge preprocessing: histogram -> dinv -> exclusive scan -> CSR scatter
// ---------------------------------------------------------------------------
__global__ void hist(const int* __restrict__ dst, int* __restrict__ cnt) {
    int e = blockIdx.x * 256 + threadIdx.x;
    unsigned d = (unsigned)dst[e];
    if (d < (unsigned)NN) atomicAdd(&cnt[d], 1);
}
__global__ void mkdinv(const int* __restrict__ cnt, float* __restrict__ dinv) {
    int i = blockIdx.x * 256 + threadIdx.x;
    int c = cnt[i]; if (c < 0) c = 0;
    dinv[i] = rsqrtf((float)c + 1.0f);     // +1 self loop
}
__global__ void scan_part(const int* __restrict__ cnt, int* __restrict__ bsum) {
    int b = blockIdx.x, t = threadIdx.x;
    int base = b * 1024 + t * 4;
    int s = cnt[base] + cnt[base + 1] + cnt[base + 2] + cnt[base + 3];
    #pragma unroll
    for (int o = 32; o >= 1; o >>= 1) s += __shfl_down(s, o);
    __shared__ int ws4[4];
    if ((t & 63) == 0) ws4[t >> 6] = s;
    __syncthreads();
    if (t == 0) bsum[b] = ws4[0] + ws4[1] + ws4[2] + ws4[3];
}
__global__ void scan_top(const int* __restrict__ bsum, int* __restrict__ boff) {
    if (threadIdx.x == 0) {
        int a = 0;
        for (int i = 0; i < 144; i++) { boff[i] = a; a += bsum[i]; }
    }
}
__global__ void scan_write(const int* __restrict__ cnt, const int* __restrict__ boff,
                           int* __restrict__ offv) {
    int b = blockIdx.x, t = threadIdx.x;
    int base = b * 1024 + t * 4;
    int v0 = cnt[base], v1 = cnt[base + 1], v2 = cnt[base + 2], v3 = cnt[base + 3];
    int ts = v0 + v1 + v2 + v3;
    __shared__ int sc[256];
    sc[t] = ts;
    __syncthreads();
    for (int o = 1; o < 256; o <<= 1) {
        int x = (t >= o) ? sc[t - o] : 0;
        __syncthreads();
        sc[t] += x;
        __syncthreads();
    }
    int excl = boff[b] + sc[t] - ts;
    offv[base] = excl;
    offv[base + 1] = excl + v0;
    offv[base + 2] = excl + v0 + v1;
    offv[base + 3] = excl + v0 + v1 + v2;
    if (b == 143 && t == 255) offv[NN] = excl + ts;
}
__global__ void scatter(const int* __restrict__ src, const int* __restrict__ dst,
                        int* __restrict__ cursor, const int* __restrict__ offv,
                        int* __restrict__ csr) {
    int e = blockIdx.x * 256 + threadIdx.x;
    unsigned d = (unsigned)dst[e];
    if (d >= (unsigned)NN) return;
    int p = atomicAdd(&cursor[d], 1);
    unsigned idx = (unsigned)(offv[d] + p);
    if (idx < (unsigned)EE) csr[idx] = src[e];
}

// ---------------------------------------------------------------------------
// GCN aggregation (h2 = dinv[row]*h[row] pre-scaled in GEMM epilogue):
// out[d] = leaky( dinv[d] * ( sum_s h2[s] + h2[d] ) + b )
// thread = (node, 8-feature chunk); short8 gathers.
// ---------------------------------------------------------------------------
template<int O>
__global__ void aggregate(const u16* __restrict__ h2, const int* __restrict__ offv,
                          const int* __restrict__ csr, const float* __restrict__ dinv,
                          const u16* __restrict__ gb, u16* __restrict__ outp) {
    constexpr int CH = O / 8;
    int t = threadIdx.x;
    int local = t / CH, c = t % CH;
    int d = blockIdx.x * (256 / CH) + local;
    size_t cof = (size_t)c * 8;
    float acc[8];
    short8 selfv = *(const short8*)(h2 + (size_t)d * O + cof);
    #pragma unroll
    for (int j = 0; j < 8; j++) acc[j] = b2f((u16)selfv[j]);
    int e0 = offv[d], e1 = offv[d + 1];
    if (e0 < 0) e0 = 0;
    if (e1 > EE) e1 = EE;
    for (int k = e0; k < e1; k++) {
        unsigned s = (unsigned)csr[k];
        if (s < (unsigned)NN) {
            short8 v = *(const short8*)(h2 + (size_t)s * O + cof);
            #pragma unroll
            for (int j = 0; j < 8; j++) acc[j] += b2f((u16)v[j]);
        }
    }
    float dd = dinv[d];
    short8 gv = *(const short8*)(gb + cof);
    short8 res;
    #pragma unroll
    for (int j = 0; j < 8; j++)
        res[j] = (short)f2b(lrelu(dd * acc[j] + b2f((u16)gv[j])));
    *(short8*)(outp + (size_t)d * O + cof) = res;
}

// ---------------------------------------------------------------------------
// Fused: depthwise 5x5 (SAME) on c[H,W,64] + concat with g3 -> linear 128->16
// -> softmax.  16x16 pixel tile + 2-halo, pixel-major LDS with stride 72
// (conflict-free for b128 pixel-varying reads).  8 channels/thread chunks.
// ---------------------------------------------------------------------------
__global__ __launch_bounds__(256) void final_fused(
        const u16* __restrict__ g3, const u16* __restrict__ cpre,
        const u16* __restrict__ dwW, const u16* __restrict__ db,
        const u16* __restrict__ lw, const u16* __restrict__ lb,
        const int* __restrict__ flag, void* __restrict__ outp) {
    __shared__ __align__(16) u16 tile[400 * 72];   // 57600 B, [pixel][ch(64)+pad8]
    __shared__ __align__(16) u16 wT[25 * 64];      // [tap][ch]
    __shared__ __align__(16) u16 wL[2048];         // [f][o]
    __shared__ float bDW[64];
    __shared__ float bL[16];
    int t = threadIdx.x;
    int tx = blockIdx.x % 24, ty = blockIdx.x / 24;
    int x0 = tx * 16 - 2, y0 = ty * 16 - 2;
    for (int i = t; i < 1600; i += 256) {
        int f = i / 25, tap = i - f * 25;
        wT[tap * 64 + f] = dwW[i];
    }
    for (int i = t; i < 2048; i += 256) wL[i] = lw[i];
    if (t < 64) bDW[t] = b2f(db[t]);
    if (t < 16) bL[t] = b2f(lb[t]);
    for (int u = t; u < 3200; u += 256) {
        int pix = u >> 3, c8 = u & 7;
        int gy = y0 + pix / 20, gx = x0 + pix % 20;
        short8 v = {0, 0, 0, 0, 0, 0, 0, 0};
        if (gy >= 0 && gy < HH && gx >= 0 && gx < WW)
            v = *(const short8*)(cpre + ((size_t)(gy * WW + gx)) * 64 + c8 * 8);
        *(short8*)&tile[pix * 72 + c8 * 8] = v;
    }
    __syncthreads();

    int px = t & 15, py = t >> 4;
    int node = (ty * 16 + py) * WW + tx * 16 + px;
    float y[16];
    #pragma unroll
    for (int o = 0; o < 16; o++) y[o] = bL[o];

    // GCN half of the concat
    const u16* g3p = g3 + (size_t)node * 64;
    for (int c8 = 0; c8 < 8; c8++) {
        short8 gvv = *(const short8*)(g3p + c8 * 8);
        #pragma unroll
        for (int j = 0; j < 8; j++) {
            float g = b2f((u16)gvv[j]);
            const short8 w0 = *(const short8*)&wL[(c8 * 8 + j) * 16];
            const short8 w1 = *(const short8*)&wL[(c8 * 8 + j) * 16 + 8];
            #pragma unroll
            for (int o = 0; o < 8; o++) {
                y[o]     += g * b2f((u16)w0[o]);
                y[o + 8] += g * b2f((u16)w1[o]);
            }
        }
    }
    // CNN half: depthwise conv on the tile, then linear
    for (int c8 = 0; c8 < 8; c8++) {
        float acc[8] = {0.f, 0.f, 0.f, 0.f, 0.f, 0.f, 0.f, 0.f};
        #pragma unroll
        for (int dy = 0; dy < 5; dy++) {
            int rbase = ((py + dy) * 20 + px) * 72 + c8 * 8;
            #pragma unroll
            for (int dx = 0; dx < 5; dx++) {
                short8 v  = *(const short8*)&tile[rbase + dx * 72];
                short8 wv = *(const short8*)&wT[(dy * 5 + dx) * 64 + c8 * 8];
                #pragma unroll
                for (int j = 0; j < 8; j++)
                    acc[j] += b2f((u16)v[j]) * b2f((u16)wv[j]);
            }
        }
        #pragma unroll
        for (int j = 0; j < 8; j++) {
            float cv = lrelu(acc[j] + bDW[c8 * 8 + j]);
            int f = 64 + c8 * 8 + j;
            const short8 w0 = *(const short8*)&wL[f * 16];
            const short8 w1 = *(const short8*)&wL[f * 16 + 8];
            #pragma unroll
            for (int o = 0; o < 8; o++) {
                y[o]     += cv * b2f((u16)w0[o]);
                y[o + 8] += cv * b2f((u16)w1[o]);
            }
        }
    }
    float mx = y[0];
    #pragma unroll
    for (int o = 1; o < 16; o++) mx = fmaxf(mx, y[o]);
    float sum = 0.f;
    #pragma unroll
    for (int o = 0; o < 16; o++) { y[o] = __expf(y[o] - mx); sum += y[o]; }
    float inv = 1.0f / fmaxf(sum, 1e-30f);
    if (*flag) {
        float* of = (float*)outp;
        #pragma unroll
        for (int o = 0; o < 16; o++) of[(size_t)node * 16 + o] = y[o] * inv;
    } else {
        u16* oh = (u16*)outp;
        #pragma unroll
        for (int o = 0; o < 16; o++) oh[(size_t)node * 16 + o] = f2b(y[o] * inv);
    }
}

// ---------------------------------------------------------------------------
// Host launcher
// ---------------------------------------------------------------------------
extern "C" void kernel_launch(void* const* d_in, const int* in_sizes, int n_in,
                              void* d_out, int out_size, void* d_ws, size_t ws_size,
                              hipStream_t stream) {
    const void* X   = d_in[0];
    const int* EIDX = (const int*)d_in[1];
    const int* esrc = EIDX;
    const int* edst = EIDX + EE;

    char* ws = (char*)d_ws;
    size_t off = 0;
    auto alloc = [&](size_t sz) -> char* {
        size_t szr = (sz + 255) & ~(size_t)255;
        char* p;
        if (off + szr <= ws_size) { p = ws + off; off += szr; }
        else { p = ws; }
        return p;
    };

    int*   dflag   = (int*)alloc(256);
    static const int pidx[NPAR] = {2,3,4,5,6,7,8,9,10,11,12,13,14,
                                   15,16,17,18,19,20,21,22,23,24,25,26,27,28};
    static const int pn[NPAR]   = {200,200,25600,128,128,128,16384,128,
                                   128,128,8192,1600,64,
                                   128,128,16384,128,
                                   128,128,16384,128,
                                   128,128,8192,64,
                                   2048,16};
    u16* parena = (u16*)alloc(100352 * 2);
    PConv pc;
    {
        int po = 0;
        for (int i = 0; i < NPAR; i++) {
            pc.src[i] = d_in[pidx[i]];
            pc.n[i] = pn[i];
            pc.off[i] = po;
            po += (pn[i] + 15) & ~15;
        }
    }
    const u16* DN1G = parena + pc.off[0];
    const u16* DN1B = parena + pc.off[1];
    const u16* DNW1 = parena + pc.off[2];
    const u16* DNB1 = parena + pc.off[3];
    const u16* DN2G = parena + pc.off[4];
    const u16* DN2B = parena + pc.off[5];
    const u16* DNW2 = parena + pc.off[6];
    const u16* DNB2 = parena + pc.off[7];
    const u16* CBNG = parena + pc.off[8];
    const u16* CBNB = parena + pc.off[9];
    const u16* CPW  = parena + pc.off[10];
    const u16* CDW  = parena + pc.off[11];
    const u16* CDB  = parena + pc.off[12];
    const u16* G1G  = parena + pc.off[13];
    const u16* G1B  = parena + pc.off[14];
    const u16* G1W  = parena + pc.off[15];
    const u16* G1BI = parena + pc.off[16];
    const u16* G2G  = parena + pc.off[17];
    const u16* G2B  = parena + pc.off[18];
    const u16* G2W  = parena + pc.off[19];
    const u16* G2BI = parena + pc.off[20];
    const u16* G3G  = parena + pc.off[21];
    const u16* G3B  = parena + pc.off[22];
    const u16* G3W  = parena + pc.off[23];
    const u16* G3BI = parena + pc.off[24];
    const u16* LINW = parena + pc.off[25];
    const u16* LINB = parena + pc.off[26];

    // zero region (contiguous)
    int*   cnt     = (int*)alloc((size_t)NN * 4);
    int*   cursor  = (int*)alloc((size_t)NN * 4);
    float* arena   = (float*)alloc(6 * 512 * 4);
    // ---- end zero region ----
    int*   offv    = (int*)alloc((size_t)(NN + 1) * 4);
    int*   bsum    = (int*)alloc(144 * 4);
    int*   boff    = (int*)alloc(144 * 4);
    float* dinvp   = (float*)alloc((size_t)NN * 4);
    float* invnorm = (float*)alloc((size_t)NN * 4);
    u16*   W1T     = (u16*)alloc(128 * 224 * 2);
    u16*   W2T     = (u16*)alloc(128 * 128 * 2);
    u16*   WpwT    = (u16*)alloc(64 * 128 * 2);
    u16*   WgT     = (u16*)alloc(128 * 128 * 2);
    float* cb1     = (float*)alloc(128 * 4);
    float* cb2     = (float*)alloc(128 * 4);
    float* cb3     = (float*)alloc(128 * 4);
    float* cbg     = (float*)alloc(128 * 4);
    int*   csr     = (int*)alloc((size_t)EE * 4);
    u16*   cbuf    = (u16*)alloc((size_t)NN * 64 * 2);    // CNN pre-dwconv "c"
    u16*   big1    = (u16*)alloc((size_t)NN * 128 * 2);   // h scratch
    u16*   big2    = (u16*)alloc((size_t)NN * 128 * 2);   // clean / g1 / g2 / g3

    const float invN = 1.0f / (float)NN;
    size_t zsz = (size_t)((char*)(arena + 6 * 512) - (char*)cnt);
    size_t zcap = ((char*)cnt >= ws && (size_t)((char*)cnt - ws) < ws_size)
                      ? ws_size - (size_t)((char*)cnt - ws) : 0;
    if (zsz > zcap) zsz = zcap;
    hipMemsetAsync(cnt, 0, zsz, stream);

    // --- dtype detection + param conversion ---
    sniff<<<1, 256, 0, stream>>>((const u16*)X, dflag);
    convert_params<<<NPAR, 256, 0, stream>>>(pc, dflag, parena);

    // --- edge preprocessing (CSR) first: dinv needed by GCN gemm epilogues ---
    hist<<<EE / 256, 256, 0, stream>>>(edst, cnt);
    mkdinv<<<NN / 256, 256, 0, stream>>>(cnt, dinvp);
    scan_part<<<144, 256, 0, stream>>>(cnt, bsum);
    scan_top<<<1, 64, 0, stream>>>(bsum, boff);
    scan_write<<<144, 256, 0, stream>>>(cnt, boff, offv);
    scatter<<<EE / 256, 256, 0, stream>>>(esrc, edst, cursor, offv, csr);

    // --- denoise ---
    stats200<<<512, 256, 0, stream>>>(X, dflag, arena + 0 * 512);
    fold_bn<200, 224, 128><<<1, 256, 0, stream>>>(arena + 0 * 512, invN, DN1G, DN1B, DNW1, DNB1, W1T, cb1);
    gemm_mfma<7, 200, 128, true, false><<<NN / 64, 256, 0, stream>>>(X, W1T, cb1, nullptr, nullptr, dflag, big1);
    stats128<<<576, 256, 0, stream>>>(big1, arena + 1 * 512);
    fold_bn<128, 128, 128><<<1, 256, 0, stream>>>(arena + 1 * 512, invN, DN2G, DN2B, DNW2, DNB2, W2T, cb2);
    gemm_mfma<4, 128, 128, true, false><<<NN / 64, 256, 0, stream>>>(big1, W2T, cb2, nullptr, nullptr, nullptr, big2);

    // --- CNN branch pointwise (dwconv fused into final) ---
    stats128<<<576, 256, 0, stream>>>(big2, arena + 2 * 512);
    fold_bn<128, 128, 64><<<1, 256, 0, stream>>>(arena + 2 * 512, invN, CBNG, CBNB, CPW, nullptr, WpwT, cb3);
    gemm_mfma<4, 128, 64, true, false><<<NN / 64, 256, 0, stream>>>(big2, WpwT, cb3, nullptr, nullptr, nullptr, cbuf);

    // --- GCN layer 1: big2(clean) -> big1(h2) -> big2(g1) ---
    rowstats<<<256, 256, 0, stream>>>(big2, invnorm, arena + 3 * 512);
    fold_bn<128, 128, 128><<<1, 256, 0, stream>>>(arena + 3 * 512, invN, G1G, G1B, G1W, nullptr, WgT, cbg);
    gemm_mfma<4, 128, 128, false, true><<<NN / 64, 256, 0, stream>>>(big2, WgT, cbg, invnorm, dinvp, nullptr, big1);
    aggregate<128><<<NN / 16, 256, 0, stream>>>(big1, offv, csr, dinvp, G1BI, big2);

    // --- GCN layer 2 ---
    rowstats<<<256, 256, 0, stream>>>(big2, invnorm, arena + 4 * 512);
    fold_bn<128, 128, 128><<<1, 256, 0, stream>>>(arena + 4 * 512, invN, G2G, G2B, G2W, nullptr, WgT, cbg);
    gemm_mfma<4, 128, 128, false, true><<<NN / 64, 256, 0, stream>>>(big2, WgT, cbg, invnorm, dinvp, nullptr, big1);
    aggregate<128><<<NN / 16, 256, 0, stream>>>(big1, offv, csr, dinvp, G2BI, big2);

    // --- GCN layer 3 (128 -> 64) ---
    rowstats<<<256, 256, 0, stream>>>(big2, invnorm, arena + 5 * 512);
    fold_bn<128, 128, 64><<<1, 256, 0, stream>>>(arena + 5 * 512, invN, G3G, G3B, G3W, nullptr, WgT, cbg);
    gemm_mfma<4, 128, 64, false, true><<<NN / 64, 256, 0, stream>>>(big2, WgT, cbg, invnorm, dinvp, nullptr, big1);
    aggregate<64><<<NN / 32, 256, 0, stream>>>(big1, offv, csr, dinvp, G3BI, big2);

    // --- fused dwconv + final linear + softmax ---
    final_fused<<<576, 256, 0, stream>>>(big2, cbuf, CDW, CDB, LINW, LINB, dflag, d_out);

    (void)in_sizes; (void)n_in; (void)out_size;
}

// Round 5
// 1285.594 us; speedup vs baseline: 1.9452x; 1.1230x over previous
//
#include <hip/hip_runtime.h>
#include <stddef.h>

// ---------------------------------------------------------------------------
// Problem constants
// ---------------------------------------------------------------------------
#define HH 384
#define WW 384
#define CC 200
#define NN 147456      // HH*WW
#define EE 1179648
#define HIDE 128
#define COUT 64
#define NCLS 16
#define BN_EPS 1e-5f

using u16 = unsigned short;
typedef __attribute__((ext_vector_type(8))) short short8;
typedef __attribute__((ext_vector_type(4))) float float4v;

__device__ __forceinline__ float b2f(u16 u) {
    union { unsigned int i; float f; } v; v.i = ((unsigned int)u) << 16; return v.f;
}
__device__ __forceinline__ u16 f2b(float f) {
    union { float f; unsigned int i; } v; v.f = f;
    unsigned int x = v.i;
    unsigned int r = (x + 0x7fffu + ((x >> 16) & 1u)) >> 16;   // RNE
    return (u16)r;
}
__device__ __forceinline__ float lrelu(float v) { return v > 0.f ? v : 0.01f * v; }

// ---------------------------------------------------------------------------
// Dtype sniffer: bf16 N(0,1) data -> ~99% of u16 high-bytes in [0x3C,0x41];
// f32 data -> ~52%.  flag=1 means inputs are float32.
// ---------------------------------------------------------------------------
__global__ void sniff(const u16* __restrict__ x, int* __restrict__ flag) {
    __shared__ int cntS;
    if (threadIdx.x == 0) cntS = 0;
    __syncthreads();
    int c = 0;
    for (int i = 0; i < 8; i++) {
        u16 h = x[threadIdx.x * 8 + i];
        int hb = (h >> 8) & 0x7F;
        if (hb >= 0x3C && hb <= 0x41) c++;
    }
    atomicAdd(&cntS, c);
    __syncthreads();
    if (threadIdx.x == 0) *flag = (cntS < 1536) ? 1 : 0;
}

// ---------------------------------------------------------------------------
// Convert all float params into a bf16 arena (copy if already bf16).
// ---------------------------------------------------------------------------
#define NPAR 27
struct PConv { const void* src[NPAR]; int n[NPAR]; int off[NPAR]; };

__global__ void convert_params(PConv pc, const int* __restrict__ flag,
                               u16* __restrict__ dst) {
    int b = blockIdx.x;
    int n = pc.n[b];
    const void* s = pc.src[b];
    u16* d = dst + pc.off[b];
    int isf = *flag;
    if (isf) {
        const float* sf = (const float*)s;
        for (int i = threadIdx.x; i < n; i += 256) d[i] = f2b(sf[i]);
    } else {
        const u16* sh = (const u16*)s;
        for (int i = threadIdx.x; i < n; i += 256) d[i] = sh[i];
    }
}

// ---------------------------------------------------------------------------
// Column stats (sum, sumsq) for BN folding
// ---------------------------------------------------------------------------
__global__ void stats200(const void* __restrict__ X, const int* __restrict__ flag,
                         float* __restrict__ arena) {
    int t = threadIdx.x;
    if (t >= CC) return;
    int r0 = blockIdx.x * 288;
    float s = 0.f, q = 0.f;
    if (*flag) {
        const float* Xf = (const float*)X;
        for (int i = 0; i < 288; i++) {
            float v = Xf[(size_t)(r0 + i) * CC + t];
            s += v; q += v * v;
        }
    } else {
        const u16* Xh = (const u16*)X;
        for (int i = 0; i < 288; i++) {
            float v = b2f(Xh[(size_t)(r0 + i) * CC + t]);
            s += v; q += v * v;
        }
    }
    atomicAdd(&arena[t], s);
    atomicAdd(&arena[256 + t], q);
}

__global__ void stats128(const u16* __restrict__ X, float* __restrict__ arena) {
    int t = threadIdx.x;
    int f = t & 127, half = t >> 7;
    int r0 = blockIdx.x * 256 + half;
    float s = 0.f, q = 0.f;
    for (int i = 0; i < 128; i++) {
        float v = b2f(X[(size_t)(r0 + 2 * i) * HIDE + f]);
        s += v; q += v * v;
    }
    atomicAdd(&arena[f], s);
    atomicAdd(&arena[256 + f], q);
}

// ---------------------------------------------------------------------------
// rowstats v2: per-row L2 inverse norm + column stats of normalized values.
// LDS-staged single pass: coalesced short8 global load; thread-per-row norm
// (no shuffles); thread-per-feature column accumulation from LDS.
// Row stride 136 u16: b128 bank-start 4t%32 -> 2-way (free); u16 column reads
// consecutive-lane -> conflict-free.  576 blocks x 256 rows.
// ---------------------------------------------------------------------------
#define RS_LD 136
__global__ __launch_bounds__(256) void rowstats(const u16* __restrict__ X,
                                                float* __restrict__ invnorm,
                                                float* __restrict__ arena) {
    __shared__ __align__(16) u16 rS[256 * RS_LD];   // 69632 B
    __shared__ float invS[256];
    int t = threadIdx.x;
    int r0 = blockIdx.x * 256;
    for (int i = t; i < 256 * 16; i += 256) {
        int r = i >> 4, c = i & 15;
        short8 v = *(const short8*)(X + (size_t)(r0 + r) * HIDE + c * 8);
        *(short8*)&rS[r * RS_LD + c * 8] = v;
    }
    __syncthreads();
    {
        float ss = 0.f;
        const u16* rp = &rS[t * RS_LD];
        #pragma unroll
        for (int c = 0; c < 16; c++) {
            short8 v = *(const short8*)(rp + c * 8);
            #pragma unroll
            for (int j = 0; j < 8; j++) { float f = b2f((u16)v[j]); ss += f * f; }
        }
        float inv = 1.0f / fmaxf(sqrtf(ss), 1e-12f);
        invS[t] = inv;
        invnorm[r0 + t] = inv;
    }
    __syncthreads();
    int f = t & 127, h = t >> 7;
    float s = 0.f, q = 0.f;
    for (int r = h; r < 256; r += 2) {
        float v = b2f(rS[r * RS_LD + f]) * invS[r];
        s += v; q += v * v;
    }
    atomicAdd(&arena[f], s);
    atomicAdd(&arena[256 + f], q);
}

// ---------------------------------------------------------------------------
// Fold BN affine into weights: W'[k,o]=a[k]*W[k,o]; cb[o]=sum_k shift[k]*W[k,o]
// Writes W' TRANSPOSED [O, KPAD] (zero padded K..KPAD).
// ---------------------------------------------------------------------------
template<int K, int KPAD, int O>
__global__ void fold_bn(const float* __restrict__ arena, float invN,
                        const u16* __restrict__ bng, const u16* __restrict__ bnb,
                        const u16* __restrict__ Wsrc, const u16* __restrict__ extrab,
                        u16* __restrict__ WT, float* __restrict__ cb) {
    __shared__ float aS[KPAD], sS[KPAD];
    int t = threadIdx.x;
    if (t < KPAD) {
        float a = 0.f, sh = 0.f;
        if (t < K) {
            float m = arena[t] * invN;
            float var = fmaxf(arena[256 + t] * invN - m * m, 0.f);
            a = b2f(bng[t]) * rsqrtf(var + BN_EPS);
            sh = b2f(bnb[t]) - m * a;
        }
        aS[t] = a; sS[t] = sh;
    }
    __syncthreads();
    if (t < O) {
        float c = extrab ? b2f(extrab[t]) : 0.f;
        for (int k = 0; k < KPAD; k++) {
            float w = (k < K) ? b2f(Wsrc[k * O + t]) : 0.f;
            c += sS[k] * w;
            WT[t * KPAD + k] = f2b(aS[k] * w);
        }
        cb[t] = c;
    }
}

// ---------------------------------------------------------------------------
// MFMA GEMM: out[N,O] = post( ... )
// SCALE=false: v = acc + cb  (+leaky if LEAKY)
// SCALE=true : v = (acc*s1[row] + cb) * s2[row]   (GCN: s1=invnorm, s2=dinv)
// ---------------------------------------------------------------------------
template<int KT, int KSRC, int O, bool LEAKY, bool SCALE>
__global__ __launch_bounds__(256) void gemm_mfma(
        const void* __restrict__ Ap, const u16* __restrict__ WT,
        const float* __restrict__ cb, const float* __restrict__ s1,
        const float* __restrict__ s2, const int* __restrict__ f32p,
        u16* __restrict__ out) {
    constexpr int KPAD = KT * 32;
    constexpr int LDA = KPAD + 8;
    __shared__ __align__(16) u16 As[64 * LDA];
    int tid = threadIdx.x;
    int row0 = blockIdx.x * 64;

    if constexpr (KSRC == KPAD) {
        const u16* A = (const u16*)Ap;
        constexpr int CH = 64 * KPAD / 8;
        for (int i = tid; i < CH; i += 256) {
            int r = i / (KPAD / 8), kc = i % (KPAD / 8);
            short8 v = *(const short8*)(A + (size_t)(row0 + r) * KSRC + kc * 8);
            *(short8*)&As[r * LDA + kc * 8] = v;
        }
    } else {
        int isf = f32p ? *f32p : 0;
        if (isf) {
            const float* A = (const float*)Ap;
            for (int i = tid; i < 64 * KPAD; i += 256) {
                int r = i / KPAD, k = i - r * KPAD;
                As[r * LDA + k] = (k < KSRC) ? f2b(A[(size_t)(row0 + r) * KSRC + k]) : (u16)0;
            }
        } else {
            const u16* A = (const u16*)Ap;
            for (int i = tid; i < 64 * KPAD; i += 256) {
                int r = i / KPAD, k = i - r * KPAD;
                As[r * LDA + k] = (k < KSRC) ? A[(size_t)(row0 + r) * KSRC + k] : (u16)0;
            }
        }
    }
    __syncthreads();

    int w = tid >> 6, lane = tid & 63, m = lane & 15, q = lane >> 4;
    const u16* Ab = &As[(w * 16 + m) * LDA];
    short8 af[KT];
    #pragma unroll
    for (int kt = 0; kt < KT; kt++) af[kt] = *(const short8*)(Ab + kt * 32 + q * 8);

    #pragma unroll
    for (int ct = 0; ct < O / 16; ct++) {
        float4v acc = {0.f, 0.f, 0.f, 0.f};
        const u16* Bb = WT + (size_t)(ct * 16 + m) * KPAD + q * 8;
        #pragma unroll
        for (int kt = 0; kt < KT; kt++) {
            short8 bf = *(const short8*)(Bb + kt * 32);
            acc = __builtin_amdgcn_mfma_f32_16x16x32_bf16(af[kt], bf, acc, 0, 0, 0);
        }
        float cbv = cb[ct * 16 + m];
        #pragma unroll
        for (int r = 0; r < 4; r++) {
            int rowg = row0 + w * 16 + q * 4 + r;
            float v = acc[r];
            if constexpr (SCALE) v = (v * s1[rowg] + cbv) * s2[rowg];
            else                 v += cbv;
            if constexpr (LEAKY) v = lrelu(v);
            out[(size_t)rowg * O + ct * 16 + m] = f2b(v);
        }
    }
}

// ---------------------------------------------------------------------------
// Edge preprocessing: histogram -> dinv -> exclusive scan -> CSR scatter
// ---------------------------------------------------------------------------
__global__ void hist(const int* __restrict__ dst, int* __restrict__ cnt) {
    int e = blockIdx.x * 256 + threadIdx.x;
    unsigned d = (unsigned)dst[e];
    if (d < (unsigned)NN) atomicAdd(&cnt[d], 1);
}
__global__ void mkdinv(const int* __restrict__ cnt, float* __restrict__ dinv) {
    int i = blockIdx.x * 256 + threadIdx.x;
    int c = cnt[i]; if (c < 0) c = 0;
    dinv[i] = rsqrtf((float)c + 1.0f);     // +1 self loop
}
__global__ void scan_part(const int* __restrict__ cnt, int* __restrict__ bsum) {
    int b = blockIdx.x, t = threadIdx.x;
    int base = b * 1024 + t * 4;
    int s = cnt[base] + cnt[base + 1] + cnt[base + 2] + cnt[base + 3];
    #pragma unroll
    for (int o = 32; o >= 1; o >>= 1) s += __shfl_down(s, o);
    __shared__ int ws4[4];
    if ((t & 63) == 0) ws4[t >> 6] = s;
    __syncthreads();
    if (t == 0) bsum[b] = ws4[0] + ws4[1] + ws4[2] + ws4[3];
}
__global__ void scan_top(const int* __restrict__ bsum, int* __restrict__ boff) {
    if (threadIdx.x == 0) {
        int a = 0;
        for (int i = 0; i < 144; i++) { boff[i] = a; a += bsum[i]; }
    }
}
__global__ void scan_write(const int* __restrict__ cnt, const int* __restrict__ boff,
                           int* __restrict__ offv) {
    int b = blockIdx.x, t = threadIdx.x;
    int base = b * 1024 + t * 4;
    int v0 = cnt[base], v1 = cnt[base + 1], v2 = cnt[base + 2], v3 = cnt[base + 3];
    int ts = v0 + v1 + v2 + v3;
    __shared__ int sc[256];
    sc[t] = ts;
    __syncthreads();
    for (int o = 1; o < 256; o <<= 1) {
        int x = (t >= o) ? sc[t - o] : 0;
        __syncthreads();
        sc[t] += x;
        __syncthreads();
    }
    int excl = boff[b] + sc[t] - ts;
    offv[base] = excl;
    offv[base + 1] = excl + v0;
    offv[base + 2] = excl + v0 + v1;
    offv[base + 3] = excl + v0 + v1 + v2;
    if (b == 143 && t == 255) offv[NN] = excl + ts;
}
__global__ void scatter(const int* __restrict__ src, const int* __restrict__ dst,
                        int* __restrict__ cursor, const int* __restrict__ offv,
                        int* __restrict__ csr) {
    int e = blockIdx.x * 256 + threadIdx.x;
    unsigned d = (unsigned)dst[e];
    if (d >= (unsigned)NN) return;
    int p = atomicAdd(&cursor[d], 1);
    unsigned idx = (unsigned)(offv[d] + p);
    if (idx < (unsigned)EE) csr[idx] = src[e];
}

// ---------------------------------------------------------------------------
// GCN aggregation (h2 = dinv[row]*h[row] pre-scaled in GEMM epilogue):
// out[d] = leaky( dinv[d] * ( sum_s h2[s] + h2[d] ) + b )
// thread = (node, 8-feature chunk); short8 gathers.
// ---------------------------------------------------------------------------
template<int O>
__global__ void aggregate(const u16* __restrict__ h2, const int* __restrict__ offv,
                          const int* __restrict__ csr, const float* __restrict__ dinv,
                          const u16* __restrict__ gb, u16* __restrict__ outp) {
    constexpr int CH = O / 8;
    int t = threadIdx.x;
    int local = t / CH, c = t % CH;
    int d = blockIdx.x * (256 / CH) + local;
    size_t cof = (size_t)c * 8;
    float acc[8];
    short8 selfv = *(const short8*)(h2 + (size_t)d * O + cof);
    #pragma unroll
    for (int j = 0; j < 8; j++) acc[j] = b2f((u16)selfv[j]);
    int e0 = offv[d], e1 = offv[d + 1];
    if (e0 < 0) e0 = 0;
    if (e1 > EE) e1 = EE;
    for (int k = e0; k < e1; k++) {
        unsigned s = (unsigned)csr[k];
        if (s < (unsigned)NN) {
            short8 v = *(const short8*)(h2 + (size_t)s * O + cof);
            #pragma unroll
            for (int j = 0; j < 8; j++) acc[j] += b2f((u16)v[j]);
        }
    }
    float dd = dinv[d];
    short8 gv = *(const short8*)(gb + cof);
    short8 res;
    #pragma unroll
    for (int j = 0; j < 8; j++)
        res[j] = (short)f2b(lrelu(dd * acc[j] + b2f((u16)gv[j])));
    *(short8*)(outp + (size_t)d * O + cof) = res;
}

// ---------------------------------------------------------------------------
// Fused: depthwise 5x5 (SAME) on c[H,W,64] + concat with g3 -> linear 128->16
// -> softmax.  16x16 pixel tile + 2-halo, pixel-major LDS with stride 72
// (conflict-free for b128 pixel-varying reads).  8 channels/thread chunks.
// ---------------------------------------------------------------------------
__global__ __launch_bounds__(256) void final_fused(
        const u16* __restrict__ g3, const u16* __restrict__ cpre,
        const u16* __restrict__ dwW, const u16* __restrict__ db,
        const u16* __restrict__ lw, const u16* __restrict__ lb,
        const int* __restrict__ flag, void* __restrict__ outp) {
    __shared__ __align__(16) u16 tile[400 * 72];   // 57600 B, [pixel][ch(64)+pad8]
    __shared__ __align__(16) u16 wT[25 * 64];      // [tap][ch]
    __shared__ __align__(16) u16 wL[2048];         // [f][o]
    __shared__ float bDW[64];
    __shared__ float bL[16];
    int t = threadIdx.x;
    int tx = blockIdx.x % 24, ty = blockIdx.x / 24;
    int x0 = tx * 16 - 2, y0 = ty * 16 - 2;
    for (int i = t; i < 1600; i += 256) {
        int f = i / 25, tap = i - f * 25;
        wT[tap * 64 + f] = dwW[i];
    }
    for (int i = t; i < 2048; i += 256) wL[i] = lw[i];
    if (t < 64) bDW[t] = b2f(db[t]);
    if (t < 16) bL[t] = b2f(lb[t]);
    for (int u = t; u < 3200; u += 256) {
        int pix = u >> 3, c8 = u & 7;
        int gy = y0 + pix / 20, gx = x0 + pix % 20;
        short8 v = {0, 0, 0, 0, 0, 0, 0, 0};
        if (gy >= 0 && gy < HH && gx >= 0 && gx < WW)
            v = *(const short8*)(cpre + ((size_t)(gy * WW + gx)) * 64 + c8 * 8);
        *(short8*)&tile[pix * 72 + c8 * 8] = v;
    }
    __syncthreads();

    int px = t & 15, py = t >> 4;
    int node = (ty * 16 + py) * WW + tx * 16 + px;
    float y[16];
    #pragma unroll
    for (int o = 0; o < 16; o++) y[o] = bL[o];

    const u16* g3p = g3 + (size_t)node * 64;
    for (int c8 = 0; c8 < 8; c8++) {
        short8 gvv = *(const short8*)(g3p + c8 * 8);
        #pragma unroll
        for (int j = 0; j < 8; j++) {
            float g = b2f((u16)gvv[j]);
            const short8 w0 = *(const short8*)&wL[(c8 * 8 + j) * 16];
            const short8 w1 = *(const short8*)&wL[(c8 * 8 + j) * 16 + 8];
            #pragma unroll
            for (int o = 0; o < 8; o++) {
                y[o]     += g * b2f((u16)w0[o]);
                y[o + 8] += g * b2f((u16)w1[o]);
            }
        }
    }
    for (int c8 = 0; c8 < 8; c8++) {
        float acc[8] = {0.f, 0.f, 0.f, 0.f, 0.f, 0.f, 0.f, 0.f};
        #pragma unroll
        for (int dy = 0; dy < 5; dy++) {
            int rbase = ((py + dy) * 20 + px) * 72 + c8 * 8;
            #pragma unroll
            for (int dx = 0; dx < 5; dx++) {
                short8 v  = *(const short8*)&tile[rbase + dx * 72];
                short8 wv = *(const short8*)&wT[(dy * 5 + dx) * 64 + c8 * 8];
                #pragma unroll
                for (int j = 0; j < 8; j++)
                    acc[j] += b2f((u16)v[j]) * b2f((u16)wv[j]);
            }
        }
        #pragma unroll
        for (int j = 0; j < 8; j++) {
            float cv = lrelu(acc[j] + bDW[c8 * 8 + j]);
            int f = 64 + c8 * 8 + j;
            const short8 w0 = *(const short8*)&wL[f * 16];
            const short8 w1 = *(const short8*)&wL[f * 16 + 8];
            #pragma unroll
            for (int o = 0; o < 8; o++) {
                y[o]     += cv * b2f((u16)w0[o]);
                y[o + 8] += cv * b2f((u16)w1[o]);
            }
        }
    }
    float mx = y[0];
    #pragma unroll
    for (int o = 1; o < 16; o++) mx = fmaxf(mx, y[o]);
    float sum = 0.f;
    #pragma unroll
    for (int o = 0; o < 16; o++) { y[o] = __expf(y[o] - mx); sum += y[o]; }
    float inv = 1.0f / fmaxf(sum, 1e-30f);
    if (*flag) {
        float* of = (float*)outp;
        #pragma unroll
        for (int o = 0; o < 16; o++) of[(size_t)node * 16 + o] = y[o] * inv;
    } else {
        u16* oh = (u16*)outp;
        #pragma unroll
        for (int o = 0; o < 16; o++) oh[(size_t)node * 16 + o] = f2b(y[o] * inv);
    }
}

// ---------------------------------------------------------------------------
// Host launcher
// ---------------------------------------------------------------------------
extern "C" void kernel_launch(void* const* d_in, const int* in_sizes, int n_in,
                              void* d_out, int out_size, void* d_ws, size_t ws_size,
                              hipStream_t stream) {
    const void* X   = d_in[0];
    const int* EIDX = (const int*)d_in[1];
    const int* esrc = EIDX;
    const int* edst = EIDX + EE;

    char* ws = (char*)d_ws;
    size_t off = 0;
    auto alloc = [&](size_t sz) -> char* {
        size_t szr = (sz + 255) & ~(size_t)255;
        char* p;
        if (off + szr <= ws_size) { p = ws + off; off += szr; }
        else { p = ws; }
        return p;
    };

    int*   dflag   = (int*)alloc(256);
    static const int pidx[NPAR] = {2,3,4,5,6,7,8,9,10,11,12,13,14,
                                   15,16,17,18,19,20,21,22,23,24,25,26,27,28};
    static const int pn[NPAR]   = {200,200,25600,128,128,128,16384,128,
                                   128,128,8192,1600,64,
                                   128,128,16384,128,
                                   128,128,16384,128,
                                   128,128,8192,64,
                                   2048,16};
    u16* parena = (u16*)alloc(100352 * 2);
    PConv pc;
    {
        int po = 0;
        for (int i = 0; i < NPAR; i++) {
            pc.src[i] = d_in[pidx[i]];
            pc.n[i] = pn[i];
            pc.off[i] = po;
            po += (pn[i] + 15) & ~15;
        }
    }
    const u16* DN1G = parena + pc.off[0];
    const u16* DN1B = parena + pc.off[1];
    const u16* DNW1 = parena + pc.off[2];
    const u16* DNB1 = parena + pc.off[3];
    const u16* DN2G = parena + pc.off[4];
    const u16* DN2B = parena + pc.off[5];
    const u16* DNW2 = parena + pc.off[6];
    const u16* DNB2 = parena + pc.off[7];
    const u16* CBNG = parena + pc.off[8];
    const u16* CBNB = parena + pc.off[9];
    const u16* CPW  = parena + pc.off[10];
    const u16* CDW  = parena + pc.off[11];
    const u16* CDB  = parena + pc.off[12];
    const u16* G1G  = parena + pc.off[13];
    const u16* G1B  = parena + pc.off[14];
    const u16* G1W  = parena + pc.off[15];
    const u16* G1BI = parena + pc.off[16];
    const u16* G2G  = parena + pc.off[17];
    const u16* G2B  = parena + pc.off[18];
    const u16* G2W  = parena + pc.off[19];
    const u16* G2BI = parena + pc.off[20];
    const u16* G3G  = parena + pc.off[21];
    const u16* G3B  = parena + pc.off[22];
    const u16* G3W  = parena + pc.off[23];
    const u16* G3BI = parena + pc.off[24];
    const u16* LINW = parena + pc.off[25];
    const u16* LINB = parena + pc.off[26];

    // zero region (contiguous)
    int*   cnt     = (int*)alloc((size_t)NN * 4);
    int*   cursor  = (int*)alloc((size_t)NN * 4);
    float* arena   = (float*)alloc(6 * 512 * 4);
    // ---- end zero region ----
    int*   offv    = (int*)alloc((size_t)(NN + 1) * 4);
    int*   bsum    = (int*)alloc(144 * 4);
    int*   boff    = (int*)alloc(144 * 4);
    float* dinvp   = (float*)alloc((size_t)NN * 4);
    float* invnorm = (float*)alloc((size_t)NN * 4);
    u16*   W1T     = (u16*)alloc(128 * 224 * 2);
    u16*   W2T     = (u16*)alloc(128 * 128 * 2);
    u16*   WpwT    = (u16*)alloc(64 * 128 * 2);
    u16*   WgT     = (u16*)alloc(128 * 128 * 2);
    float* cb1     = (float*)alloc(128 * 4);
    float* cb2     = (float*)alloc(128 * 4);
    float* cb3     = (float*)alloc(128 * 4);
    float* cbg     = (float*)alloc(128 * 4);
    int*   csr     = (int*)alloc((size_t)EE * 4);
    u16*   cbuf    = (u16*)alloc((size_t)NN * 64 * 2);    // CNN pre-dwconv "c"
    u16*   big1    = (u16*)alloc((size_t)NN * 128 * 2);   // h scratch
    u16*   big2    = (u16*)alloc((size_t)NN * 128 * 2);   // clean / g1 / g2 / g3

    const float invN = 1.0f / (float)NN;
    size_t zsz = (size_t)((char*)(arena + 6 * 512) - (char*)cnt);
    size_t zcap = ((char*)cnt >= ws && (size_t)((char*)cnt - ws) < ws_size)
                      ? ws_size - (size_t)((char*)cnt - ws) : 0;
    if (zsz > zcap) zsz = zcap;
    hipMemsetAsync(cnt, 0, zsz, stream);

    // --- dtype detection + param conversion ---
    sniff<<<1, 256, 0, stream>>>((const u16*)X, dflag);
    convert_params<<<NPAR, 256, 0, stream>>>(pc, dflag, parena);

    // --- edge preprocessing (CSR) first: dinv needed by GCN gemm epilogues ---
    hist<<<EE / 256, 256, 0, stream>>>(edst, cnt);
    mkdinv<<<NN / 256, 256, 0, stream>>>(cnt, dinvp);
    scan_part<<<144, 256, 0, stream>>>(cnt, bsum);
    scan_top<<<1, 64, 0, stream>>>(bsum, boff);
    scan_write<<<144, 256, 0, stream>>>(cnt, boff, offv);
    scatter<<<EE / 256, 256, 0, stream>>>(esrc, edst, cursor, offv, csr);

    // --- denoise ---
    stats200<<<512, 256, 0, stream>>>(X, dflag, arena + 0 * 512);
    fold_bn<200, 224, 128><<<1, 256, 0, stream>>>(arena + 0 * 512, invN, DN1G, DN1B, DNW1, DNB1, W1T, cb1);
    gemm_mfma<7, 200, 128, true, false><<<NN / 64, 256, 0, stream>>>(X, W1T, cb1, nullptr, nullptr, dflag, big1);
    stats128<<<576, 256, 0, stream>>>(big1, arena + 1 * 512);
    fold_bn<128, 128, 128><<<1, 256, 0, stream>>>(arena + 1 * 512, invN, DN2G, DN2B, DNW2, DNB2, W2T, cb2);
    gemm_mfma<4, 128, 128, true, false><<<NN / 64, 256, 0, stream>>>(big1, W2T, cb2, nullptr, nullptr, nullptr, big2);

    // --- CNN branch pointwise (dwconv fused into final) ---
    stats128<<<576, 256, 0, stream>>>(big2, arena + 2 * 512);
    fold_bn<128, 128, 64><<<1, 256, 0, stream>>>(arena + 2 * 512, invN, CBNG, CBNB, CPW, nullptr, WpwT, cb3);
    gemm_mfma<4, 128, 64, true, false><<<NN / 64, 256, 0, stream>>>(big2, WpwT, cb3, nullptr, nullptr, nullptr, cbuf);

    // --- GCN layer 1: big2(clean) -> big1(h2) -> big2(g1) ---
    rowstats<<<576, 256, 0, stream>>>(big2, invnorm, arena + 3 * 512);
    fold_bn<128, 128, 128><<<1, 256, 0, stream>>>(arena + 3 * 512, invN, G1G, G1B, G1W, nullptr, WgT, cbg);
    gemm_mfma<4, 128, 128, false, true><<<NN / 64, 256, 0, stream>>>(big2, WgT, cbg, invnorm, dinvp, nullptr, big1);
    aggregate<128><<<NN / 16, 256, 0, stream>>>(big1, offv, csr, dinvp, G1BI, big2);

    // --- GCN layer 2 ---
    rowstats<<<576, 256, 0, stream>>>(big2, invnorm, arena + 4 * 512);
    fold_bn<128, 128, 128><<<1, 256, 0, stream>>>(arena + 4 * 512, invN, G2G, G2B, G2W, nullptr, WgT, cbg);
    gemm_mfma<4, 128, 128, false, true><<<NN / 64, 256, 0, stream>>>(big2, WgT, cbg, invnorm, dinvp, nullptr, big1);
    aggregate<128><<<NN / 16, 256, 0, stream>>>(big1, offv, csr, dinvp, G2BI, big2);

    // --- GCN layer 3 (128 -> 64) ---
    rowstats<<<576, 256, 0, stream>>>(big2, invnorm, arena + 5 * 512);
    fold_bn<128, 128, 64><<<1, 256, 0, stream>>>(arena + 5 * 512, invN, G3G, G3B, G3W, nullptr, WgT, cbg);
    gemm_mfma<4, 128, 64, false, true><<<NN / 64, 256, 0, stream>>>(big2, WgT, cbg, invnorm, dinvp, nullptr, big1);
    aggregate<64><<<NN / 32, 256, 0, stream>>>(big1, offv, csr, dinvp, G3BI, big2);

    // --- fused dwconv + final linear + softmax ---
    final_fused<<<576, 256, 0, stream>>>(big2, cbuf, CDW, CDB, LINW, LINB, dflag, d_out);

    (void)in_sizes; (void)n_in; (void)out_size;
}

// Round 6
// 1263.933 us; speedup vs baseline: 1.9785x; 1.0171x over previous
//
#include <hip/hip_runtime.h>
#include <stddef.h>

// ---------------------------------------------------------------------------
// Problem constants
// ---------------------------------------------------------------------------
#define HH 384
#define WW 384
#define CC 200
#define NN 147456      // HH*WW
#define EE 1179648
#define HIDE 128
#define COUT 64
#define NCLS 16
#define BN_EPS 1e-5f

using u16 = unsigned short;
typedef __attribute__((ext_vector_type(8))) short short8;
typedef __attribute__((ext_vector_type(4))) float float4v;

__device__ __forceinline__ float b2f(u16 u) {
    union { unsigned int i; float f; } v; v.i = ((unsigned int)u) << 16; return v.f;
}
__device__ __forceinline__ u16 f2b(float f) {
    union { float f; unsigned int i; } v; v.f = f;
    unsigned int x = v.i;
    unsigned int r = (x + 0x7fffu + ((x >> 16) & 1u)) >> 16;   // RNE
    return (u16)r;
}
__device__ __forceinline__ float lrelu(float v) { return v > 0.f ? v : 0.01f * v; }

// ---------------------------------------------------------------------------
// Dtype sniffer: flag=1 means inputs are float32 (input observed bf16 in
// practice; kept for robustness, cost ~2 µs).
// ---------------------------------------------------------------------------
__global__ void sniff(const u16* __restrict__ x, int* __restrict__ flag) {
    __shared__ int cntS;
    if (threadIdx.x == 0) cntS = 0;
    __syncthreads();
    int c = 0;
    for (int i = 0; i < 8; i++) {
        u16 h = x[threadIdx.x * 8 + i];
        int hb = (h >> 8) & 0x7F;
        if (hb >= 0x3C && hb <= 0x41) c++;
    }
    atomicAdd(&cntS, c);
    __syncthreads();
    if (threadIdx.x == 0) *flag = (cntS < 1536) ? 1 : 0;
}

// ---------------------------------------------------------------------------
// Convert all float params into a bf16 arena (copy if already bf16).
// ---------------------------------------------------------------------------
#define NPAR 27
struct PConv { const void* src[NPAR]; int n[NPAR]; int off[NPAR]; };

__global__ void convert_params(PConv pc, const int* __restrict__ flag,
                               u16* __restrict__ dst) {
    int b = blockIdx.x;
    int n = pc.n[b];
    const void* s = pc.src[b];
    u16* d = dst + pc.off[b];
    int isf = *flag;
    if (isf) {
        const float* sf = (const float*)s;
        for (int i = threadIdx.x; i < n; i += 256) d[i] = f2b(sf[i]);
    } else {
        const u16* sh = (const u16*)s;
        for (int i = threadIdx.x; i < n; i += 256) d[i] = sh[i];
    }
}

// ---------------------------------------------------------------------------
// stats200 v2: LDS-staged column stats of X[N,200].
// Coalesced short8 tile load (128 rows x 200 u16 = 51200 B), then per-column
// accumulation from LDS (u16 reads, 2-way bank aliasing = free).
// grid 1152 x 256.
// ---------------------------------------------------------------------------
__global__ __launch_bounds__(256) void stats200(const void* __restrict__ X,
                                                const int* __restrict__ flag,
                                                float* __restrict__ arena) {
    __shared__ __align__(16) u16 s[128 * 200];   // 51200 B
    int t = threadIdx.x;
    int r0 = blockIdx.x * 128;
    if (*flag) {
        const float* Xf = (const float*)X;
        for (int i = t; i < 128 * 25; i += 256) {
            int r = i / 25, kc = i - r * 25;
            const float* p = Xf + (size_t)(r0 + r) * CC + kc * 8;
            short8 v;
            #pragma unroll
            for (int j = 0; j < 8; j++) v[j] = (short)f2b(p[j]);
            *(short8*)&s[r * 200 + kc * 8] = v;
        }
    } else {
        const u16* Xh = (const u16*)X;
        for (int i = t; i < 128 * 25; i += 256) {
            int r = i / 25, kc = i - r * 25;
            *(short8*)&s[r * 200 + kc * 8] =
                *(const short8*)(Xh + (size_t)(r0 + r) * CC + kc * 8);
        }
    }
    __syncthreads();
    if (t < CC) {
        float sum = 0.f, sq = 0.f;
        for (int r = 0; r < 128; r++) {
            float v = b2f(s[r * 200 + t]);
            sum += v; sq += v * v;
        }
        atomicAdd(&arena[t], sum);
        atomicAdd(&arena[256 + t], sq);
    }
}

__global__ void stats128(const u16* __restrict__ X, float* __restrict__ arena) {
    int t = threadIdx.x;
    int f = t & 127, half = t >> 7;
    int r0 = blockIdx.x * 256 + half;
    float s = 0.f, q = 0.f;
    for (int i = 0; i < 128; i++) {
        float v = b2f(X[(size_t)(r0 + 2 * i) * HIDE + f]);
        s += v; q += v * v;
    }
    atomicAdd(&arena[f], s);
    atomicAdd(&arena[256 + f], q);
}

// ---------------------------------------------------------------------------
// rowstats: per-row L2 inverse norm + column stats of normalized values.
// LDS-staged; 576 blocks x 256 rows.
// ---------------------------------------------------------------------------
#define RS_LD 136
__global__ __launch_bounds__(256) void rowstats(const u16* __restrict__ X,
                                                float* __restrict__ invnorm,
                                                float* __restrict__ arena) {
    __shared__ __align__(16) u16 rS[256 * RS_LD];   // 69632 B
    __shared__ float invS[256];
    int t = threadIdx.x;
    int r0 = blockIdx.x * 256;
    for (int i = t; i < 256 * 16; i += 256) {
        int r = i >> 4, c = i & 15;
        short8 v = *(const short8*)(X + (size_t)(r0 + r) * HIDE + c * 8);
        *(short8*)&rS[r * RS_LD + c * 8] = v;
    }
    __syncthreads();
    {
        float ss = 0.f;
        const u16* rp = &rS[t * RS_LD];
        #pragma unroll
        for (int c = 0; c < 16; c++) {
            short8 v = *(const short8*)(rp + c * 8);
            #pragma unroll
            for (int j = 0; j < 8; j++) { float f = b2f((u16)v[j]); ss += f * f; }
        }
        float inv = 1.0f / fmaxf(sqrtf(ss), 1e-12f);
        invS[t] = inv;
        invnorm[r0 + t] = inv;
    }
    __syncthreads();
    int f = t & 127, h = t >> 7;
    float s = 0.f, q = 0.f;
    for (int r = h; r < 256; r += 2) {
        float v = b2f(rS[r * RS_LD + f]) * invS[r];
        s += v; q += v * v;
    }
    atomicAdd(&arena[f], s);
    atomicAdd(&arena[256 + f], q);
}

// ---------------------------------------------------------------------------
// Fold BN affine into weights: W'[k,o]=a[k]*W[k,o]; cb[o]=sum_k shift[k]*W[k,o]
// Writes W' TRANSPOSED [O, KPAD] (zero padded K..KPAD).
// ---------------------------------------------------------------------------
template<int K, int KPAD, int O>
__global__ void fold_bn(const float* __restrict__ arena, float invN,
                        const u16* __restrict__ bng, const u16* __restrict__ bnb,
                        const u16* __restrict__ Wsrc, const u16* __restrict__ extrab,
                        u16* __restrict__ WT, float* __restrict__ cb) {
    __shared__ float aS[KPAD], sS[KPAD];
    int t = threadIdx.x;
    if (t < KPAD) {
        float a = 0.f, sh = 0.f;
        if (t < K) {
            float m = arena[t] * invN;
            float var = fmaxf(arena[256 + t] * invN - m * m, 0.f);
            a = b2f(bng[t]) * rsqrtf(var + BN_EPS);
            sh = b2f(bnb[t]) - m * a;
        }
        aS[t] = a; sS[t] = sh;
    }
    __syncthreads();
    if (t < O) {
        float c = extrab ? b2f(extrab[t]) : 0.f;
        for (int k = 0; k < KPAD; k++) {
            float w = (k < K) ? b2f(Wsrc[k * O + t]) : 0.f;
            c += sS[k] * w;
            WT[t * KPAD + k] = f2b(aS[k] * w);
        }
        cb[t] = c;
    }
}

// ---------------------------------------------------------------------------
// MFMA GEMM: out[N,O] = post( ... )
// SCALE=false: v = acc + cb  (+leaky if LEAKY)
// SCALE=true : v = (acc*s1[row] + cb) * s2[row]   (GCN: s1=invnorm, s2=dinv)
// Staging fully short8-vectorized (KSRC must be a multiple of 8).
// ---------------------------------------------------------------------------
template<int KT, int KSRC, int O, bool LEAKY, bool SCALE>
__global__ __launch_bounds__(256) void gemm_mfma(
        const void* __restrict__ Ap, const u16* __restrict__ WT,
        const float* __restrict__ cb, const float* __restrict__ s1,
        const float* __restrict__ s2, const int* __restrict__ f32p,
        u16* __restrict__ out) {
    constexpr int KPAD = KT * 32;
    constexpr int LDA = KPAD + 8;
    constexpr int CHR = KPAD / 8;          // short8 chunks per padded row
    constexpr int CHD = KSRC / 8;          // data chunks per row
    __shared__ __align__(16) u16 As[64 * LDA];
    int tid = threadIdx.x;
    int row0 = blockIdx.x * 64;

    int isf = f32p ? *f32p : 0;
    if (isf) {
        const float* A = (const float*)Ap;
        for (int i = tid; i < 64 * CHR; i += 256) {
            int r = i / CHR, kc = i - r * CHR;
            short8 v = {0, 0, 0, 0, 0, 0, 0, 0};
            if (kc < CHD) {
                const float* p = A + (size_t)(row0 + r) * KSRC + kc * 8;
                #pragma unroll
                for (int j = 0; j < 8; j++) v[j] = (short)f2b(p[j]);
            }
            *(short8*)&As[r * LDA + kc * 8] = v;
        }
    } else {
        const u16* A = (const u16*)Ap;
        for (int i = tid; i < 64 * CHR; i += 256) {
            int r = i / CHR, kc = i - r * CHR;
            short8 v = {0, 0, 0, 0, 0, 0, 0, 0};
            if (kc < CHD)
                v = *(const short8*)(A + (size_t)(row0 + r) * KSRC + kc * 8);
            *(short8*)&As[r * LDA + kc * 8] = v;
        }
    }
    __syncthreads();

    int w = tid >> 6, lane = tid & 63, m = lane & 15, q = lane >> 4;
    const u16* Ab = &As[(w * 16 + m) * LDA];
    short8 af[KT];
    #pragma unroll
    for (int kt = 0; kt < KT; kt++) af[kt] = *(const short8*)(Ab + kt * 32 + q * 8);

    #pragma unroll
    for (int ct = 0; ct < O / 16; ct++) {
        float4v acc = {0.f, 0.f, 0.f, 0.f};
        const u16* Bb = WT + (size_t)(ct * 16 + m) * KPAD + q * 8;
        #pragma unroll
        for (int kt = 0; kt < KT; kt++) {
            short8 bf = *(const short8*)(Bb + kt * 32);
            acc = __builtin_amdgcn_mfma_f32_16x16x32_bf16(af[kt], bf, acc, 0, 0, 0);
        }
        float cbv = cb[ct * 16 + m];
        #pragma unroll
        for (int r = 0; r < 4; r++) {
            int rowg = row0 + w * 16 + q * 4 + r;
            float v = acc[r];
            if constexpr (SCALE) v = (v * s1[rowg] + cbv) * s2[rowg];
            else                 v += cbv;
            if constexpr (LEAKY) v = lrelu(v);
            out[(size_t)rowg * O + ct * 16 + m] = f2b(v);
        }
    }
}

// ---------------------------------------------------------------------------
// Edge preprocessing: histogram -> dinv -> exclusive scan -> CSR scatter
// ---------------------------------------------------------------------------
__global__ void hist(const int* __restrict__ dst, int* __restrict__ cnt) {
    int e = blockIdx.x * 256 + threadIdx.x;
    unsigned d = (unsigned)dst[e];
    if (d < (unsigned)NN) atomicAdd(&cnt[d], 1);
}
__global__ void mkdinv(const int* __restrict__ cnt, float* __restrict__ dinv) {
    int i = blockIdx.x * 256 + threadIdx.x;
    int c = cnt[i]; if (c < 0) c = 0;
    dinv[i] = rsqrtf((float)c + 1.0f);     // +1 self loop
}
__global__ void scan_part(const int* __restrict__ cnt, int* __restrict__ bsum) {
    int b = blockIdx.x, t = threadIdx.x;
    int base = b * 1024 + t * 4;
    int s = cnt[base] + cnt[base + 1] + cnt[base + 2] + cnt[base + 3];
    #pragma unroll
    for (int o = 32; o >= 1; o >>= 1) s += __shfl_down(s, o);
    __shared__ int ws4[4];
    if ((t & 63) == 0) ws4[t >> 6] = s;
    __syncthreads();
    if (t == 0) bsum[b] = ws4[0] + ws4[1] + ws4[2] + ws4[3];
}
__global__ void scan_top(const int* __restrict__ bsum, int* __restrict__ boff) {
    if (threadIdx.x == 0) {
        int a = 0;
        for (int i = 0; i < 144; i++) { boff[i] = a; a += bsum[i]; }
    }
}
__global__ void scan_write(const int* __restrict__ cnt, const int* __restrict__ boff,
                           int* __restrict__ offv) {
    int b = blockIdx.x, t = threadIdx.x;
    int base = b * 1024 + t * 4;
    int v0 = cnt[base], v1 = cnt[base + 1], v2 = cnt[base + 2], v3 = cnt[base + 3];
    int ts = v0 + v1 + v2 + v3;
    __shared__ int sc[256];
    sc[t] = ts;
    __syncthreads();
    for (int o = 1; o < 256; o <<= 1) {
        int x = (t >= o) ? sc[t - o] : 0;
        __syncthreads();
        sc[t] += x;
        __syncthreads();
    }
    int excl = boff[b] + sc[t] - ts;
    offv[base] = excl;
    offv[base + 1] = excl + v0;
    offv[base + 2] = excl + v0 + v1;
    offv[base + 3] = excl + v0 + v1 + v2;
    if (b == 143 && t == 255) offv[NN] = excl + ts;
}
__global__ void scatter(const int* __restrict__ src, const int* __restrict__ dst,
                        int* __restrict__ cursor, const int* __restrict__ offv,
                        int* __restrict__ csr) {
    int e = blockIdx.x * 256 + threadIdx.x;
    unsigned d = (unsigned)dst[e];
    if (d >= (unsigned)NN) return;
    int p = atomicAdd(&cursor[d], 1);
    unsigned idx = (unsigned)(offv[d] + p);
    if (idx < (unsigned)EE) csr[idx] = src[e];
}

// ---------------------------------------------------------------------------
// GCN aggregation (h2 = dinv[row]*h[row] pre-scaled in GEMM epilogue):
// out[d] = leaky( dinv[d] * ( sum_s h2[s] + h2[d] ) + b )
// thread = (node, 8-feature chunk); short8 gathers.
// ---------------------------------------------------------------------------
template<int O>
__global__ void aggregate(const u16* __restrict__ h2, const int* __restrict__ offv,
                          const int* __restrict__ csr, const float* __restrict__ dinv,
                          const u16* __restrict__ gb, u16* __restrict__ outp) {
    constexpr int CH = O / 8;
    int t = threadIdx.x;
    int local = t / CH, c = t % CH;
    int d = blockIdx.x * (256 / CH) + local;
    size_t cof = (size_t)c * 8;
    float acc[8];
    short8 selfv = *(const short8*)(h2 + (size_t)d * O + cof);
    #pragma unroll
    for (int j = 0; j < 8; j++) acc[j] = b2f((u16)selfv[j]);
    int e0 = offv[d], e1 = offv[d + 1];
    if (e0 < 0) e0 = 0;
    if (e1 > EE) e1 = EE;
    for (int k = e0; k < e1; k++) {
        unsigned s = (unsigned)csr[k];
        if (s < (unsigned)NN) {
            short8 v = *(const short8*)(h2 + (size_t)s * O + cof);
            #pragma unroll
            for (int j = 0; j < 8; j++) acc[j] += b2f((u16)v[j]);
        }
    }
    float dd = dinv[d];
    short8 gv = *(const short8*)(gb + cof);
    short8 res;
    #pragma unroll
    for (int j = 0; j < 8; j++)
        res[j] = (short)f2b(lrelu(dd * acc[j] + b2f((u16)gv[j])));
    *(short8*)(outp + (size_t)d * O + cof) = res;
}

// ---------------------------------------------------------------------------
// Fused: depthwise 5x5 (SAME) on c[H,W,64] + concat with g3 -> linear 128->16
// -> softmax.  16x16 pixel tile + 2-halo, pixel-major LDS with stride 72.
// ---------------------------------------------------------------------------
__global__ __launch_bounds__(256) void final_fused(
        const u16* __restrict__ g3, const u16* __restrict__ cpre,
        const u16* __restrict__ dwW, const u16* __restrict__ db,
        const u16* __restrict__ lw, const u16* __restrict__ lb,
        const int* __restrict__ flag, void* __restrict__ outp) {
    __shared__ __align__(16) u16 tile[400 * 72];   // 57600 B, [pixel][ch(64)+pad8]
    __shared__ __align__(16) u16 wT[25 * 64];      // [tap][ch]
    __shared__ __align__(16) u16 wL[2048];         // [f][o]
    __shared__ float bDW[64];
    __shared__ float bL[16];
    int t = threadIdx.x;
    int tx = blockIdx.x % 24, ty = blockIdx.x / 24;
    int x0 = tx * 16 - 2, y0 = ty * 16 - 2;
    for (int i = t; i < 1600; i += 256) {
        int f = i / 25, tap = i - f * 25;
        wT[tap * 64 + f] = dwW[i];
    }
    for (int i = t; i < 2048; i += 256) wL[i] = lw[i];
    if (t < 64) bDW[t] = b2f(db[t]);
    if (t < 16) bL[t] = b2f(lb[t]);
    for (int u = t; u < 3200; u += 256) {
        int pix = u >> 3, c8 = u & 7;
        int gy = y0 + pix / 20, gx = x0 + pix % 20;
        short8 v = {0, 0, 0, 0, 0, 0, 0, 0};
        if (gy >= 0 && gy < HH && gx >= 0 && gx < WW)
            v = *(const short8*)(cpre + ((size_t)(gy * WW + gx)) * 64 + c8 * 8);
        *(short8*)&tile[pix * 72 + c8 * 8] = v;
    }
    __syncthreads();

    int px = t & 15, py = t >> 4;
    int node = (ty * 16 + py) * WW + tx * 16 + px;
    float y[16];
    #pragma unroll
    for (int o = 0; o < 16; o++) y[o] = bL[o];

    const u16* g3p = g3 + (size_t)node * 64;
    for (int c8 = 0; c8 < 8; c8++) {
        short8 gvv = *(const short8*)(g3p + c8 * 8);
        #pragma unroll
        for (int j = 0; j < 8; j++) {
            float g = b2f((u16)gvv[j]);
            const short8 w0 = *(const short8*)&wL[(c8 * 8 + j) * 16];
            const short8 w1 = *(const short8*)&wL[(c8 * 8 + j) * 16 + 8];
            #pragma unroll
            for (int o = 0; o < 8; o++) {
                y[o]     += g * b2f((u16)w0[o]);
                y[o + 8] += g * b2f((u16)w1[o]);
            }
        }
    }
    for (int c8 = 0; c8 < 8; c8++) {
        float acc[8] = {0.f, 0.f, 0.f, 0.f, 0.f, 0.f, 0.f, 0.f};
        #pragma unroll
        for (int dy = 0; dy < 5; dy++) {
            int rbase = ((py + dy) * 20 + px) * 72 + c8 * 8;
            #pragma unroll
            for (int dx = 0; dx < 5; dx++) {
                short8 v  = *(const short8*)&tile[rbase + dx * 72];
                short8 wv = *(const short8*)&wT[(dy * 5 + dx) * 64 + c8 * 8];
                #pragma unroll
                for (int j = 0; j < 8; j++)
                    acc[j] += b2f((u16)v[j]) * b2f((u16)wv[j]);
            }
        }
        #pragma unroll
        for (int j = 0; j < 8; j++) {
            float cv = lrelu(acc[j] + bDW[c8 * 8 + j]);
            int f = 64 + c8 * 8 + j;
            const short8 w0 = *(const short8*)&wL[f * 16];
            const short8 w1 = *(const short8*)&wL[f * 16 + 8];
            #pragma unroll
            for (int o = 0; o < 8; o++) {
                y[o]     += cv * b2f((u16)w0[o]);
                y[o + 8] += cv * b2f((u16)w1[o]);
            }
        }
    }
    float mx = y[0];
    #pragma unroll
    for (int o = 1; o < 16; o++) mx = fmaxf(mx, y[o]);
    float sum = 0.f;
    #pragma unroll
    for (int o = 0; o < 16; o++) { y[o] = __expf(y[o] - mx); sum += y[o]; }
    float inv = 1.0f / fmaxf(sum, 1e-30f);
    if (*flag) {
        float* of = (float*)outp;
        #pragma unroll
        for (int o = 0; o < 16; o++) of[(size_t)node * 16 + o] = y[o] * inv;
    } else {
        u16* oh = (u16*)outp;
        #pragma unroll
        for (int o = 0; o < 16; o++) oh[(size_t)node * 16 + o] = f2b(y[o] * inv);
    }
}

// ---------------------------------------------------------------------------
// Host launcher
// ---------------------------------------------------------------------------
extern "C" void kernel_launch(void* const* d_in, const int* in_sizes, int n_in,
                              void* d_out, int out_size, void* d_ws, size_t ws_size,
                              hipStream_t stream) {
    const void* X   = d_in[0];
    const int* EIDX = (const int*)d_in[1];
    const int* esrc = EIDX;
    const int* edst = EIDX + EE;

    char* ws = (char*)d_ws;
    size_t off = 0;
    auto alloc = [&](size_t sz) -> char* {
        size_t szr = (sz + 255) & ~(size_t)255;
        char* p;
        if (off + szr <= ws_size) { p = ws + off; off += szr; }
        else { p = ws; }
        return p;
    };

    int*   dflag   = (int*)alloc(256);
    static const int pidx[NPAR] = {2,3,4,5,6,7,8,9,10,11,12,13,14,
                                   15,16,17,18,19,20,21,22,23,24,25,26,27,28};
    static const int pn[NPAR]   = {200,200,25600,128,128,128,16384,128,
                                   128,128,8192,1600,64,
                                   128,128,16384,128,
                                   128,128,16384,128,
                                   128,128,8192,64,
                                   2048,16};
    u16* parena = (u16*)alloc(100352 * 2);
    PConv pc;
    {
        int po = 0;
        for (int i = 0; i < NPAR; i++) {
            pc.src[i] = d_in[pidx[i]];
            pc.n[i] = pn[i];
            pc.off[i] = po;
            po += (pn[i] + 15) & ~15;
        }
    }
    const u16* DN1G = parena + pc.off[0];
    const u16* DN1B = parena + pc.off[1];
    const u16* DNW1 = parena + pc.off[2];
    const u16* DNB1 = parena + pc.off[3];
    const u16* DN2G = parena + pc.off[4];
    const u16* DN2B = parena + pc.off[5];
    const u16* DNW2 = parena + pc.off[6];
    const u16* DNB2 = parena + pc.off[7];
    const u16* CBNG = parena + pc.off[8];
    const u16* CBNB = parena + pc.off[9];
    const u16* CPW  = parena + pc.off[10];
    const u16* CDW  = parena + pc.off[11];
    const u16* CDB  = parena + pc.off[12];
    const u16* G1G  = parena + pc.off[13];
    const u16* G1B  = parena + pc.off[14];
    const u16* G1W  = parena + pc.off[15];
    const u16* G1BI = parena + pc.off[16];
    const u16* G2G  = parena + pc.off[17];
    const u16* G2B  = parena + pc.off[18];
    const u16* G2W  = parena + pc.off[19];
    const u16* G2BI = parena + pc.off[20];
    const u16* G3G  = parena + pc.off[21];
    const u16* G3B  = parena + pc.off[22];
    const u16* G3W  = parena + pc.off[23];
    const u16* G3BI = parena + pc.off[24];
    const u16* LINW = parena + pc.off[25];
    const u16* LINB = parena + pc.off[26];

    // zero region (contiguous)
    int*   cnt     = (int*)alloc((size_t)NN * 4);
    int*   cursor  = (int*)alloc((size_t)NN * 4);
    float* arena   = (float*)alloc(6 * 512 * 4);
    // ---- end zero region ----
    int*   offv    = (int*)alloc((size_t)(NN + 1) * 4);
    int*   bsum    = (int*)alloc(144 * 4);
    int*   boff    = (int*)alloc(144 * 4);
    float* dinvp   = (float*)alloc((size_t)NN * 4);
    float* invnorm = (float*)alloc((size_t)NN * 4);
    u16*   W1T     = (u16*)alloc(128 * 224 * 2);
    u16*   W2T     = (u16*)alloc(128 * 128 * 2);
    u16*   WpwT    = (u16*)alloc(64 * 128 * 2);
    u16*   WgT     = (u16*)alloc(128 * 128 * 2);
    float* cb1     = (float*)alloc(128 * 4);
    float* cb2     = (float*)alloc(128 * 4);
    float* cb3     = (float*)alloc(128 * 4);
    float* cbg     = (float*)alloc(128 * 4);
    int*   csr     = (int*)alloc((size_t)EE * 4);
    u16*   cbuf    = (u16*)alloc((size_t)NN * 64 * 2);    // CNN pre-dwconv "c"
    u16*   big1    = (u16*)alloc((size_t)NN * 128 * 2);   // h scratch
    u16*   big2    = (u16*)alloc((size_t)NN * 128 * 2);   // clean / g1 / g2 / g3

    const float invN = 1.0f / (float)NN;
    size_t zsz = (size_t)((char*)(arena + 6 * 512) - (char*)cnt);
    size_t zcap = ((char*)cnt >= ws && (size_t)((char*)cnt - ws) < ws_size)
                      ? ws_size - (size_t)((char*)cnt - ws) : 0;
    if (zsz > zcap) zsz = zcap;
    hipMemsetAsync(cnt, 0, zsz, stream);

    // --- dtype detection + param conversion ---
    sniff<<<1, 256, 0, stream>>>((const u16*)X, dflag);
    convert_params<<<NPAR, 256, 0, stream>>>(pc, dflag, parena);

    // --- edge preprocessing (CSR) first: dinv needed by GCN gemm epilogues ---
    hist<<<EE / 256, 256, 0, stream>>>(edst, cnt);
    mkdinv<<<NN / 256, 256, 0, stream>>>(cnt, dinvp);
    scan_part<<<144, 256, 0, stream>>>(cnt, bsum);
    scan_top<<<1, 64, 0, stream>>>(bsum, boff);
    scan_write<<<144, 256, 0, stream>>>(cnt, boff, offv);
    scatter<<<EE / 256, 256, 0, stream>>>(esrc, edst, cursor, offv, csr);

    // --- denoise ---
    stats200<<<1152, 256, 0, stream>>>(X, dflag, arena + 0 * 512);
    fold_bn<200, 224, 128><<<1, 256, 0, stream>>>(arena + 0 * 512, invN, DN1G, DN1B, DNW1, DNB1, W1T, cb1);
    gemm_mfma<7, 200, 128, true, false><<<NN / 64, 256, 0, stream>>>(X, W1T, cb1, nullptr, nullptr, dflag, big1);
    stats128<<<576, 256, 0, stream>>>(big1, arena + 1 * 512);
    fold_bn<128, 128, 128><<<1, 256, 0, stream>>>(arena + 1 * 512, invN, DN2G, DN2B, DNW2, DNB2, W2T, cb2);
    gemm_mfma<4, 128, 128, true, false><<<NN / 64, 256, 0, stream>>>(big1, W2T, cb2, nullptr, nullptr, nullptr, big2);

    // --- CNN branch pointwise (dwconv fused into final) ---
    stats128<<<576, 256, 0, stream>>>(big2, arena + 2 * 512);
    fold_bn<128, 128, 64><<<1, 256, 0, stream>>>(arena + 2 * 512, invN, CBNG, CBNB, CPW, nullptr, WpwT, cb3);
    gemm_mfma<4, 128, 64, true, false><<<NN / 64, 256, 0, stream>>>(big2, WpwT, cb3, nullptr, nullptr, nullptr, cbuf);

    // --- GCN layer 1: big2(clean) -> big1(h2) -> big2(g1) ---
    rowstats<<<576, 256, 0, stream>>>(big2, invnorm, arena + 3 * 512);
    fold_bn<128, 128, 128><<<1, 256, 0, stream>>>(arena + 3 * 512, invN, G1G, G1B, G1W, nullptr, WgT, cbg);
    gemm_mfma<4, 128, 128, false, true><<<NN / 64, 256, 0, stream>>>(big2, WgT, cbg, invnorm, dinvp, nullptr, big1);
    aggregate<128><<<NN / 16, 256, 0, stream>>>(big1, offv, csr, dinvp, G1BI, big2);

    // --- GCN layer 2 ---
    rowstats<<<576, 256, 0, stream>>>(big2, invnorm, arena + 4 * 512);
    fold_bn<128, 128, 128><<<1, 256, 0, stream>>>(arena + 4 * 512, invN, G2G, G2B, G2W, nullptr, WgT, cbg);
    gemm_mfma<4, 128, 128, false, true><<<NN / 64, 256, 0, stream>>>(big2, WgT, cbg, invnorm, dinvp, nullptr, big1);
    aggregate<128><<<NN / 16, 256, 0, stream>>>(big1, offv, csr, dinvp, G2BI, big2);

    // --- GCN layer 3 (128 -> 64) ---
    rowstats<<<576, 256, 0, stream>>>(big2, invnorm, arena + 5 * 512);
    fold_bn<128, 128, 64><<<1, 256, 0, stream>>>(arena + 5 * 512, invN, G3G, G3B, G3W, nullptr, WgT, cbg);
    gemm_mfma<4, 128, 64, false, true><<<NN / 64, 256, 0, stream>>>(big2, WgT, cbg, invnorm, dinvp, nullptr, big1);
    aggregate<64><<<NN / 32, 256, 0, stream>>>(big1, offv, csr, dinvp, G3BI, big2);

    // --- fused dwconv + final linear + softmax ---
    final_fused<<<576, 256, 0, stream>>>(big2, cbuf, CDW, CDB, LINW, LINB, dflag, d_out);

    (void)in_sizes; (void)n_in; (void)out_size;
}

// Round 7
// 1153.971 us; speedup vs baseline: 2.1671x; 1.0953x over previous
//
#include <hip/hip_runtime.h>
#include <stddef.h>

// ---------------------------------------------------------------------------
// Problem constants
// ---------------------------------------------------------------------------
#define HH 384
#define WW 384
#define CC 200
#define NN 147456      // HH*WW
#define EE 1179648
#define HIDE 128
#define COUT 64
#define NCLS 16
#define BN_EPS 1e-5f

using u16 = unsigned short;
typedef __attribute__((ext_vector_type(8))) short short8;
typedef __attribute__((ext_vector_type(4))) float float4v;

__device__ __forceinline__ float b2f(u16 u) {
    union { unsigned int i; float f; } v; v.i = ((unsigned int)u) << 16; return v.f;
}
__device__ __forceinline__ u16 f2b(float f) {
    union { float f; unsigned int i; } v; v.f = f;
    unsigned int x = v.i;
    unsigned int r = (x + 0x7fffu + ((x >> 16) & 1u)) >> 16;   // RNE
    return (u16)r;
}
__device__ __forceinline__ float lrelu(float v) { return v > 0.f ? v : 0.01f * v; }

// ---------------------------------------------------------------------------
// Dtype sniffer: flag=1 means inputs are float32.
// ---------------------------------------------------------------------------
__global__ void sniff(const u16* __restrict__ x, int* __restrict__ flag) {
    __shared__ int cntS;
    if (threadIdx.x == 0) cntS = 0;
    __syncthreads();
    int c = 0;
    for (int i = 0; i < 8; i++) {
        u16 h = x[threadIdx.x * 8 + i];
        int hb = (h >> 8) & 0x7F;
        if (hb >= 0x3C && hb <= 0x41) c++;
    }
    atomicAdd(&cntS, c);
    __syncthreads();
    if (threadIdx.x == 0) *flag = (cntS < 1536) ? 1 : 0;
}

// ---------------------------------------------------------------------------
// Convert all float params into a bf16 arena (copy if already bf16).
// ---------------------------------------------------------------------------
#define NPAR 27
struct PConv { const void* src[NPAR]; int n[NPAR]; int off[NPAR]; };

__global__ void convert_params(PConv pc, const int* __restrict__ flag,
                               u16* __restrict__ dst) {
    int b = blockIdx.x;
    int n = pc.n[b];
    const void* s = pc.src[b];
    u16* d = dst + pc.off[b];
    int isf = *flag;
    if (isf) {
        const float* sf = (const float*)s;
        for (int i = threadIdx.x; i < n; i += 256) d[i] = f2b(sf[i]);
    } else {
        const u16* sh = (const u16*)s;
        for (int i = threadIdx.x; i < n; i += 256) d[i] = sh[i];
    }
}

// ---------------------------------------------------------------------------
// stats200: LDS-staged column stats of X[N,200].  grid 1152 x 256.
// ---------------------------------------------------------------------------
__global__ __launch_bounds__(256) void stats200(const void* __restrict__ X,
                                                const int* __restrict__ flag,
                                                float* __restrict__ arena) {
    __shared__ __align__(16) u16 s[128 * 200];   // 51200 B
    int t = threadIdx.x;
    int r0 = blockIdx.x * 128;
    if (*flag) {
        const float* Xf = (const float*)X;
        for (int i = t; i < 128 * 25; i += 256) {
            int r = i / 25, kc = i - r * 25;
            const float* p = Xf + (size_t)(r0 + r) * CC + kc * 8;
            short8 v;
            #pragma unroll
            for (int j = 0; j < 8; j++) v[j] = (short)f2b(p[j]);
            *(short8*)&s[r * 200 + kc * 8] = v;
        }
    } else {
        const u16* Xh = (const u16*)X;
        for (int i = t; i < 128 * 25; i += 256) {
            int r = i / 25, kc = i - r * 25;
            *(short8*)&s[r * 200 + kc * 8] =
                *(const short8*)(Xh + (size_t)(r0 + r) * CC + kc * 8);
        }
    }
    __syncthreads();
    if (t < CC) {
        float sum = 0.f, sq = 0.f;
        for (int r = 0; r < 128; r++) {
            float v = b2f(s[r * 200 + t]);
            sum += v; sq += v * v;
        }
        atomicAdd(&arena[t], sum);
        atomicAdd(&arena[256 + t], sq);
    }
}

__global__ void stats128(const u16* __restrict__ X, float* __restrict__ arena) {
    int t = threadIdx.x;
    int f = t & 127, half = t >> 7;
    int r0 = blockIdx.x * 256 + half;
    float s = 0.f, q = 0.f;
    for (int i = 0; i < 128; i++) {
        float v = b2f(X[(size_t)(r0 + 2 * i) * HIDE + f]);
        s += v; q += v * v;
    }
    atomicAdd(&arena[f], s);
    atomicAdd(&arena[256 + f], q);
}

// ---------------------------------------------------------------------------
// rowstats: per-row L2 inverse norm + column stats of normalized values.
// LDS-staged; 576 blocks x 256 rows.
// ---------------------------------------------------------------------------
#define RS_LD 136
__global__ __launch_bounds__(256) void rowstats(const u16* __restrict__ X,
                                                float* __restrict__ invnorm,
                                                float* __restrict__ arena) {
    __shared__ __align__(16) u16 rS[256 * RS_LD];   // 69632 B
    __shared__ float invS[256];
    int t = threadIdx.x;
    int r0 = blockIdx.x * 256;
    for (int i = t; i < 256 * 16; i += 256) {
        int r = i >> 4, c = i & 15;
        short8 v = *(const short8*)(X + (size_t)(r0 + r) * HIDE + c * 8);
        *(short8*)&rS[r * RS_LD + c * 8] = v;
    }
    __syncthreads();
    {
        float ss = 0.f;
        const u16* rp = &rS[t * RS_LD];
        #pragma unroll
        for (int c = 0; c < 16; c++) {
            short8 v = *(const short8*)(rp + c * 8);
            #pragma unroll
            for (int j = 0; j < 8; j++) { float f = b2f((u16)v[j]); ss += f * f; }
        }
        float inv = 1.0f / fmaxf(sqrtf(ss), 1e-12f);
        invS[t] = inv;
        invnorm[r0 + t] = inv;
    }
    __syncthreads();
    int f = t & 127, h = t >> 7;
    float s = 0.f, q = 0.f;
    for (int r = h; r < 256; r += 2) {
        float v = b2f(rS[r * RS_LD + f]) * invS[r];
        s += v; q += v * v;
    }
    atomicAdd(&arena[f], s);
    atomicAdd(&arena[256 + f], q);
}

// ---------------------------------------------------------------------------
// fold_bn v2 (latency-parallel): grid = ceil(O/4) blocks, 4 wave-groups each.
// Group g folds output row o = blk*4+g: lanes stride k (coalesced WT writes,
// independent gathers of Wsrc), wave-shuffle reduce for cb[o].
// ---------------------------------------------------------------------------
template<int K, int KPAD, int O>
__global__ __launch_bounds__(256) void fold_bn(
        const float* __restrict__ arena, float invN,
        const u16* __restrict__ bng, const u16* __restrict__ bnb,
        const u16* __restrict__ Wsrc, const u16* __restrict__ extrab,
        u16* __restrict__ WT, float* __restrict__ cb) {
    __shared__ float aS[KPAD], sS[KPAD];
    int t = threadIdx.x;
    if (t < KPAD) {
        float a = 0.f, sh = 0.f;
        if (t < K) {
            float m = arena[t] * invN;
            float var = fmaxf(arena[256 + t] * invN - m * m, 0.f);
            a = b2f(bng[t]) * rsqrtf(var + BN_EPS);
            sh = b2f(bnb[t]) - m * a;
        }
        aS[t] = a; sS[t] = sh;
    }
    __syncthreads();
    int g = t >> 6, l = t & 63;
    int o = blockIdx.x * 4 + g;
    if (o < O) {
        float c = 0.f;
        #pragma unroll
        for (int k = l; k < KPAD; k += 64) {
            float w = (k < K) ? b2f(Wsrc[k * O + o]) : 0.f;
            c += sS[k] * w;
            WT[o * KPAD + k] = f2b(aS[k] * w);
        }
        #pragma unroll
        for (int s = 32; s >= 1; s >>= 1) c += __shfl_down(c, s);
        if (l == 0) cb[o] = c + (extrab ? b2f(extrab[o]) : 0.f);
    }
}

// ---------------------------------------------------------------------------
// MFMA GEMM: out[N,O] = post( ... )
// SCALE=false: v = acc + cb  (+leaky if LEAKY)
// SCALE=true : v = (acc*s1[row] + cb) * s2[row]   (GCN: s1=invnorm, s2=dinv)
// ---------------------------------------------------------------------------
template<int KT, int KSRC, int O, bool LEAKY, bool SCALE>
__global__ __launch_bounds__(256) void gemm_mfma(
        const void* __restrict__ Ap, const u16* __restrict__ WT,
        const float* __restrict__ cb, const float* __restrict__ s1,
        const float* __restrict__ s2, const int* __restrict__ f32p,
        u16* __restrict__ out) {
    constexpr int KPAD = KT * 32;
    constexpr int LDA = KPAD + 8;
    constexpr int CHR = KPAD / 8;
    constexpr int CHD = KSRC / 8;
    __shared__ __align__(16) u16 As[64 * LDA];
    int tid = threadIdx.x;
    int row0 = blockIdx.x * 64;

    int isf = f32p ? *f32p : 0;
    if (isf) {
        const float* A = (const float*)Ap;
        for (int i = tid; i < 64 * CHR; i += 256) {
            int r = i / CHR, kc = i - r * CHR;
            short8 v = {0, 0, 0, 0, 0, 0, 0, 0};
            if (kc < CHD) {
                const float* p = A + (size_t)(row0 + r) * KSRC + kc * 8;
                #pragma unroll
                for (int j = 0; j < 8; j++) v[j] = (short)f2b(p[j]);
            }
            *(short8*)&As[r * LDA + kc * 8] = v;
        }
    } else {
        const u16* A = (const u16*)Ap;
        for (int i = tid; i < 64 * CHR; i += 256) {
            int r = i / CHR, kc = i - r * CHR;
            short8 v = {0, 0, 0, 0, 0, 0, 0, 0};
            if (kc < CHD)
                v = *(const short8*)(A + (size_t)(row0 + r) * KSRC + kc * 8);
            *(short8*)&As[r * LDA + kc * 8] = v;
        }
    }
    __syncthreads();

    int w = tid >> 6, lane = tid & 63, m = lane & 15, q = lane >> 4;
    const u16* Ab = &As[(w * 16 + m) * LDA];
    short8 af[KT];
    #pragma unroll
    for (int kt = 0; kt < KT; kt++) af[kt] = *(const short8*)(Ab + kt * 32 + q * 8);

    #pragma unroll
    for (int ct = 0; ct < O / 16; ct++) {
        float4v acc = {0.f, 0.f, 0.f, 0.f};
        const u16* Bb = WT + (size_t)(ct * 16 + m) * KPAD + q * 8;
        #pragma unroll
        for (int kt = 0; kt < KT; kt++) {
            short8 bf = *(const short8*)(Bb + kt * 32);
            acc = __builtin_amdgcn_mfma_f32_16x16x32_bf16(af[kt], bf, acc, 0, 0, 0);
        }
        float cbv = cb[ct * 16 + m];
        #pragma unroll
        for (int r = 0; r < 4; r++) {
            int rowg = row0 + w * 16 + q * 4 + r;
            float v = acc[r];
            if constexpr (SCALE) v = (v * s1[rowg] + cbv) * s2[rowg];
            else                 v += cbv;
            if constexpr (LEAKY) v = lrelu(v);
            out[(size_t)rowg * O + ct * 16 + m] = f2b(v);
        }
    }
}

// ---------------------------------------------------------------------------
// Edge preprocessing: histogram -> dinv -> exclusive scan -> CSR scatter
// ---------------------------------------------------------------------------
__global__ void hist(const int* __restrict__ dst, int* __restrict__ cnt) {
    int e = blockIdx.x * 256 + threadIdx.x;
    unsigned d = (unsigned)dst[e];
    if (d < (unsigned)NN) atomicAdd(&cnt[d], 1);
}
__global__ void mkdinv(const int* __restrict__ cnt, float* __restrict__ dinv) {
    int i = blockIdx.x * 256 + threadIdx.x;
    int c = cnt[i]; if (c < 0) c = 0;
    dinv[i] = rsqrtf((float)c + 1.0f);     // +1 self loop
}
__global__ void scan_part(const int* __restrict__ cnt, int* __restrict__ bsum) {
    int b = blockIdx.x, t = threadIdx.x;
    int base = b * 1024 + t * 4;
    int s = cnt[base] + cnt[base + 1] + cnt[base + 2] + cnt[base + 3];
    #pragma unroll
    for (int o = 32; o >= 1; o >>= 1) s += __shfl_down(s, o);
    __shared__ int ws4[4];
    if ((t & 63) == 0) ws4[t >> 6] = s;
    __syncthreads();
    if (t == 0) bsum[b] = ws4[0] + ws4[1] + ws4[2] + ws4[3];
}
__global__ void scan_top(const int* __restrict__ bsum, int* __restrict__ boff) {
    if (threadIdx.x == 0) {
        int a = 0;
        for (int i = 0; i < 144; i++) { boff[i] = a; a += bsum[i]; }
    }
}
__global__ void scan_write(const int* __restrict__ cnt, const int* __restrict__ boff,
                           int* __restrict__ offv) {
    int b = blockIdx.x, t = threadIdx.x;
    int base = b * 1024 + t * 4;
    int v0 = cnt[base], v1 = cnt[base + 1], v2 = cnt[base + 2], v3 = cnt[base + 3];
    int ts = v0 + v1 + v2 + v3;
    __shared__ int sc[256];
    sc[t] = ts;
    __syncthreads();
    for (int o = 1; o < 256; o <<= 1) {
        int x = (t >= o) ? sc[t - o] : 0;
        __syncthreads();
        sc[t] += x;
        __syncthreads();
    }
    int excl = boff[b] + sc[t] - ts;
    offv[base] = excl;
    offv[base + 1] = excl + v0;
    offv[base + 2] = excl + v0 + v1;
    offv[base + 3] = excl + v0 + v1 + v2;
    if (b == 143 && t == 255) offv[NN] = excl + ts;
}
__global__ void scatter(const int* __restrict__ src, const int* __restrict__ dst,
                        int* __restrict__ cursor, const int* __restrict__ offv,
                        int* __restrict__ csr) {
    int e = blockIdx.x * 256 + threadIdx.x;
    unsigned d = (unsigned)dst[e];
    if (d >= (unsigned)NN) return;
    int p = atomicAdd(&cursor[d], 1);
    unsigned idx = (unsigned)(offv[d] + p);
    if (idx < (unsigned)EE) csr[idx] = src[e];
}

// ---------------------------------------------------------------------------
// GCN aggregation (h2 = dinv[row]*h[row] pre-scaled in GEMM epilogue):
// out[d] = leaky( dinv[d] * ( sum_s h2[s] + h2[d] ) + b )
// ---------------------------------------------------------------------------
template<int O>
__global__ void aggregate(const u16* __restrict__ h2, const int* __restrict__ offv,
                          const int* __restrict__ csr, const float* __restrict__ dinv,
                          const u16* __restrict__ gb, u16* __restrict__ outp) {
    constexpr int CH = O / 8;
    int t = threadIdx.x;
    int local = t / CH, c = t % CH;
    int d = blockIdx.x * (256 / CH) + local;
    size_t cof = (size_t)c * 8;
    float acc[8];
    short8 selfv = *(const short8*)(h2 + (size_t)d * O + cof);
    #pragma unroll
    for (int j = 0; j < 8; j++) acc[j] = b2f((u16)selfv[j]);
    int e0 = offv[d], e1 = offv[d + 1];
    if (e0 < 0) e0 = 0;
    if (e1 > EE) e1 = EE;
    for (int k = e0; k < e1; k++) {
        unsigned s = (unsigned)csr[k];
        if (s < (unsigned)NN) {
            short8 v = *(const short8*)(h2 + (size_t)s * O + cof);
            #pragma unroll
            for (int j = 0; j < 8; j++) acc[j] += b2f((u16)v[j]);
        }
    }
    float dd = dinv[d];
    short8 gv = *(const short8*)(gb + cof);
    short8 res;
    #pragma unroll
    for (int j = 0; j < 8; j++)
        res[j] = (short)f2b(lrelu(dd * acc[j] + b2f((u16)gv[j])));
    *(short8*)(outp + (size_t)d * O + cof) = res;
}

// ---------------------------------------------------------------------------
// Fused: depthwise 5x5 (SAME) on c[H,W,64] + concat with g3 -> linear 128->16
// -> softmax.  16x16 pixel tile + 2-halo, pixel-major LDS with stride 72.
// ---------------------------------------------------------------------------
__global__ __launch_bounds__(256) void final_fused(
        const u16* __restrict__ g3, const u16* __restrict__ cpre,
        const u16* __restrict__ dwW, const u16* __restrict__ db,
        const u16* __restrict__ lw, const u16* __restrict__ lb,
        const int* __restrict__ flag, void* __restrict__ outp) {
    __shared__ __align__(16) u16 tile[400 * 72];   // 57600 B
    __shared__ __align__(16) u16 wT[25 * 64];      // [tap][ch]
    __shared__ __align__(16) u16 wL[2048];         // [f][o]
    __shared__ float bDW[64];
    __shared__ float bL[16];
    int t = threadIdx.x;
    int tx = blockIdx.x % 24, ty = blockIdx.x / 24;
    int x0 = tx * 16 - 2, y0 = ty * 16 - 2;
    for (int i = t; i < 1600; i += 256) {
        int f = i / 25, tap = i - f * 25;
        wT[tap * 64 + f] = dwW[i];
    }
    for (int i = t; i < 2048; i += 256) wL[i] = lw[i];
    if (t < 64) bDW[t] = b2f(db[t]);
    if (t < 16) bL[t] = b2f(lb[t]);
    for (int u = t; u < 3200; u += 256) {
        int pix = u >> 3, c8 = u & 7;
        int gy = y0 + pix / 20, gx = x0 + pix % 20;
        short8 v = {0, 0, 0, 0, 0, 0, 0, 0};
        if (gy >= 0 && gy < HH && gx >= 0 && gx < WW)
            v = *(const short8*)(cpre + ((size_t)(gy * WW + gx)) * 64 + c8 * 8);
        *(short8*)&tile[pix * 72 + c8 * 8] = v;
    }
    __syncthreads();

    int px = t & 15, py = t >> 4;
    int node = (ty * 16 + py) * WW + tx * 16 + px;
    float y[16];
    #pragma unroll
    for (int o = 0; o < 16; o++) y[o] = bL[o];

    const u16* g3p = g3 + (size_t)node * 64;
    for (int c8 = 0; c8 < 8; c8++) {
        short8 gvv = *(const short8*)(g3p + c8 * 8);
        #pragma unroll
        for (int j = 0; j < 8; j++) {
            float g = b2f((u16)gvv[j]);
            const short8 w0 = *(const short8*)&wL[(c8 * 8 + j) * 16];
            const short8 w1 = *(const short8*)&wL[(c8 * 8 + j) * 16 + 8];
            #pragma unroll
            for (int o = 0; o < 8; o++) {
                y[o]     += g * b2f((u16)w0[o]);
                y[o + 8] += g * b2f((u16)w1[o]);
            }
        }
    }
    for (int c8 = 0; c8 < 8; c8++) {
        float acc[8] = {0.f, 0.f, 0.f, 0.f, 0.f, 0.f, 0.f, 0.f};
        #pragma unroll
        for (int dy = 0; dy < 5; dy++) {
            int rbase = ((py + dy) * 20 + px) * 72 + c8 * 8;
            #pragma unroll
            for (int dx = 0; dx < 5; dx++) {
                short8 v  = *(const short8*)&tile[rbase + dx * 72];
                short8 wv = *(const short8*)&wT[(dy * 5 + dx) * 64 + c8 * 8];
                #pragma unroll
                for (int j = 0; j < 8; j++)
                    acc[j] += b2f((u16)v[j]) * b2f((u16)wv[j]);
            }
        }
        #pragma unroll
        for (int j = 0; j < 8; j++) {
            float cv = lrelu(acc[j] + bDW[c8 * 8 + j]);
            int f = 64 + c8 * 8 + j;
            const short8 w0 = *(const short8*)&wL[f * 16];
            const short8 w1 = *(const short8*)&wL[f * 16 + 8];
            #pragma unroll
            for (int o = 0; o < 8; o++) {
                y[o]     += cv * b2f((u16)w0[o]);
                y[o + 8] += cv * b2f((u16)w1[o]);
            }
        }
    }
    float mx = y[0];
    #pragma unroll
    for (int o = 1; o < 16; o++) mx = fmaxf(mx, y[o]);
    float sum = 0.f;
    #pragma unroll
    for (int o = 0; o < 16; o++) { y[o] = __expf(y[o] - mx); sum += y[o]; }
    float inv = 1.0f / fmaxf(sum, 1e-30f);
    if (*flag) {
        float* of = (float*)outp;
        #pragma unroll
        for (int o = 0; o < 16; o++) of[(size_t)node * 16 + o] = y[o] * inv;
    } else {
        u16* oh = (u16*)outp;
        #pragma unroll
        for (int o = 0; o < 16; o++) oh[(size_t)node * 16 + o] = f2b(y[o] * inv);
    }
}

// ---------------------------------------------------------------------------
// Host launcher
// ---------------------------------------------------------------------------
extern "C" void kernel_launch(void* const* d_in, const int* in_sizes, int n_in,
                              void* d_out, int out_size, void* d_ws, size_t ws_size,
                              hipStream_t stream) {
    const void* X   = d_in[0];
    const int* EIDX = (const int*)d_in[1];
    const int* esrc = EIDX;
    const int* edst = EIDX + EE;

    char* ws = (char*)d_ws;
    size_t off = 0;
    auto alloc = [&](size_t sz) -> char* {
        size_t szr = (sz + 255) & ~(size_t)255;
        char* p;
        if (off + szr <= ws_size) { p = ws + off; off += szr; }
        else { p = ws; }
        return p;
    };

    int*   dflag   = (int*)alloc(256);
    static const int pidx[NPAR] = {2,3,4,5,6,7,8,9,10,11,12,13,14,
                                   15,16,17,18,19,20,21,22,23,24,25,26,27,28};
    static const int pn[NPAR]   = {200,200,25600,128,128,128,16384,128,
                                   128,128,8192,1600,64,
                                   128,128,16384,128,
                                   128,128,16384,128,
                                   128,128,8192,64,
                                   2048,16};
    u16* parena = (u16*)alloc(100352 * 2);
    PConv pc;
    {
        int po = 0;
        for (int i = 0; i < NPAR; i++) {
            pc.src[i] = d_in[pidx[i]];
            pc.n[i] = pn[i];
            pc.off[i] = po;
            po += (pn[i] + 15) & ~15;
        }
    }
    const u16* DN1G = parena + pc.off[0];
    const u16* DN1B = parena + pc.off[1];
    const u16* DNW1 = parena + pc.off[2];
    const u16* DNB1 = parena + pc.off[3];
    const u16* DN2G = parena + pc.off[4];
    const u16* DN2B = parena + pc.off[5];
    const u16* DNW2 = parena + pc.off[6];
    const u16* DNB2 = parena + pc.off[7];
    const u16* CBNG = parena + pc.off[8];
    const u16* CBNB = parena + pc.off[9];
    const u16* CPW  = parena + pc.off[10];
    const u16* CDW  = parena + pc.off[11];
    const u16* CDB  = parena + pc.off[12];
    const u16* G1G  = parena + pc.off[13];
    const u16* G1B  = parena + pc.off[14];
    const u16* G1W  = parena + pc.off[15];
    const u16* G1BI = parena + pc.off[16];
    const u16* G2G  = parena + pc.off[17];
    const u16* G2B  = parena + pc.off[18];
    const u16* G2W  = parena + pc.off[19];
    const u16* G2BI = parena + pc.off[20];
    const u16* G3G  = parena + pc.off[21];
    const u16* G3B  = parena + pc.off[22];
    const u16* G3W  = parena + pc.off[23];
    const u16* G3BI = parena + pc.off[24];
    const u16* LINW = parena + pc.off[25];
    const u16* LINB = parena + pc.off[26];

    // zero region (contiguous)
    int*   cnt     = (int*)alloc((size_t)NN * 4);
    int*   cursor  = (int*)alloc((size_t)NN * 4);
    float* arena   = (float*)alloc(6 * 512 * 4);
    // ---- end zero region ----
    int*   offv    = (int*)alloc((size_t)(NN + 1) * 4);
    int*   bsum    = (int*)alloc(144 * 4);
    int*   boff    = (int*)alloc(144 * 4);
    float* dinvp   = (float*)alloc((size_t)NN * 4);
    float* invnorm = (float*)alloc((size_t)NN * 4);
    u16*   W1T     = (u16*)alloc(128 * 224 * 2);
    u16*   W2T     = (u16*)alloc(128 * 128 * 2);
    u16*   WpwT    = (u16*)alloc(64 * 128 * 2);
    u16*   WgT     = (u16*)alloc(128 * 128 * 2);
    float* cb1     = (float*)alloc(128 * 4);
    float* cb2     = (float*)alloc(128 * 4);
    float* cb3     = (float*)alloc(128 * 4);
    float* cbg     = (float*)alloc(128 * 4);
    int*   csr     = (int*)alloc((size_t)EE * 4);
    u16*   cbuf    = (u16*)alloc((size_t)NN * 64 * 2);    // CNN pre-dwconv "c"
    u16*   big1    = (u16*)alloc((size_t)NN * 128 * 2);   // h scratch
    u16*   big2    = (u16*)alloc((size_t)NN * 128 * 2);   // clean / g1 / g2 / g3

    const float invN = 1.0f / (float)NN;
    size_t zsz = (size_t)((char*)(arena + 6 * 512) - (char*)cnt);
    size_t zcap = ((char*)cnt >= ws && (size_t)((char*)cnt - ws) < ws_size)
                      ? ws_size - (size_t)((char*)cnt - ws) : 0;
    if (zsz > zcap) zsz = zcap;
    hipMemsetAsync(cnt, 0, zsz, stream);

    // --- dtype detection + param conversion ---
    sniff<<<1, 256, 0, stream>>>((const u16*)X, dflag);
    convert_params<<<NPAR, 256, 0, stream>>>(pc, dflag, parena);

    // --- edge preprocessing (CSR) first: dinv needed by GCN gemm epilogues ---
    hist<<<EE / 256, 256, 0, stream>>>(edst, cnt);
    mkdinv<<<NN / 256, 256, 0, stream>>>(cnt, dinvp);
    scan_part<<<144, 256, 0, stream>>>(cnt, bsum);
    scan_top<<<1, 64, 0, stream>>>(bsum, boff);
    scan_write<<<144, 256, 0, stream>>>(cnt, boff, offv);
    scatter<<<EE / 256, 256, 0, stream>>>(esrc, edst, cursor, offv, csr);

    // --- denoise ---
    stats200<<<1152, 256, 0, stream>>>(X, dflag, arena + 0 * 512);
    fold_bn<200, 224, 128><<<32, 256, 0, stream>>>(arena + 0 * 512, invN, DN1G, DN1B, DNW1, DNB1, W1T, cb1);
    gemm_mfma<7, 200, 128, true, false><<<NN / 64, 256, 0, stream>>>(X, W1T, cb1, nullptr, nullptr, dflag, big1);
    stats128<<<576, 256, 0, stream>>>(big1, arena + 1 * 512);
    fold_bn<128, 128, 128><<<32, 256, 0, stream>>>(arena + 1 * 512, invN, DN2G, DN2B, DNW2, DNB2, W2T, cb2);
    gemm_mfma<4, 128, 128, true, false><<<NN / 64, 256, 0, stream>>>(big1, W2T, cb2, nullptr, nullptr, nullptr, big2);

    // --- CNN branch pointwise (dwconv fused into final) ---
    stats128<<<576, 256, 0, stream>>>(big2, arena + 2 * 512);
    fold_bn<128, 128, 64><<<16, 256, 0, stream>>>(arena + 2 * 512, invN, CBNG, CBNB, CPW, nullptr, WpwT, cb3);
    gemm_mfma<4, 128, 64, true, false><<<NN / 64, 256, 0, stream>>>(big2, WpwT, cb3, nullptr, nullptr, nullptr, cbuf);

    // --- GCN layer 1: big2(clean) -> big1(h2) -> big2(g1) ---
    rowstats<<<576, 256, 0, stream>>>(big2, invnorm, arena + 3 * 512);
    fold_bn<128, 128, 128><<<32, 256, 0, stream>>>(arena + 3 * 512, invN, G1G, G1B, G1W, nullptr, WgT, cbg);
    gemm_mfma<4, 128, 128, false, true><<<NN / 64, 256, 0, stream>>>(big2, WgT, cbg, invnorm, dinvp, nullptr, big1);
    aggregate<128><<<NN / 16, 256, 0, stream>>>(big1, offv, csr, dinvp, G1BI, big2);

    // --- GCN layer 2 ---
    rowstats<<<576, 256, 0, stream>>>(big2, invnorm, arena + 4 * 512);
    fold_bn<128, 128, 128><<<32, 256, 0, stream>>>(arena + 4 * 512, invN, G2G, G2B, G2W, nullptr, WgT, cbg);
    gemm_mfma<4, 128, 128, false, true><<<NN / 64, 256, 0, stream>>>(big2, WgT, cbg, invnorm, dinvp, nullptr, big1);
    aggregate<128><<<NN / 16, 256, 0, stream>>>(big1, offv, csr, dinvp, G2BI, big2);

    // --- GCN layer 3 (128 -> 64) ---
    rowstats<<<576, 256, 0, stream>>>(big2, invnorm, arena + 5 * 512);
    fold_bn<128, 128, 64><<<16, 256, 0, stream>>>(arena + 5 * 512, invN, G3G, G3B, G3W, nullptr, WgT, cbg);
    gemm_mfma<4, 128, 64, false, true><<<NN / 64, 256, 0, stream>>>(big2, WgT, cbg, invnorm, dinvp, nullptr, big1);
    aggregate<64><<<NN / 32, 256, 0, stream>>>(big1, offv, csr, dinvp, G3BI, big2);

    // --- fused dwconv + final linear + softmax ---
    final_fused<<<576, 256, 0, stream>>>(big2, cbuf, CDW, CDB, LINW, LINB, dflag, d_out);

    (void)in_sizes; (void)n_in; (void)out_size;
}